// Round 1
// baseline (446.028 us; speedup 1.0000x reference)
//
#include <hip/hip_runtime.h>

#define S 4096
#define FIN 128
#define FOUT 64
#define H 8
#define ALPHA 0.2f

// ---------------------------------------------------------------------------
// Kernel 1: h[h,i,f] = X[i,:]·W[h,:,f];  f1[h,i]=h·a1[h], f2[h,i]=h·a2[h]
// grid (S/4, H), block 256. Wave = one row (64 f lanes) -> shuffle reduce.
// ---------------------------------------------------------------------------
__global__ __launch_bounds__(256) void k_proj(const float* __restrict__ X,
                                              const float* __restrict__ W,
                                              const float* __restrict__ a1,
                                              const float* __restrict__ a2,
                                              float* __restrict__ hbuf,
                                              float* __restrict__ f1,
                                              float* __restrict__ f2) {
    __shared__ float xs[4][FIN];
    const int h  = blockIdx.y;
    const int i0 = blockIdx.x * 4;
    const int t  = threadIdx.x;
    for (int idx = t; idx < 4 * FIN; idx += 256) {
        xs[idx >> 7][idx & 127] = X[(i0 + (idx >> 7)) * FIN + (idx & 127)];
    }
    __syncthreads();
    const int f = t & 63, r = t >> 6;
    const float* Wh = W + h * FIN * FOUT;
    float acc = 0.f;
#pragma unroll 8
    for (int k = 0; k < FIN; ++k)
        acc += xs[r][k] * Wh[k * FOUT + f];
    const int row = i0 + r;
    hbuf[((h * S) + row) * FOUT + f] = acc;
    float v1 = acc * a1[h * FOUT + f];
    float v2 = acc * a2[h * FOUT + f];
#pragma unroll
    for (int off = 32; off; off >>= 1) {
        v1 += __shfl_xor(v1, off, 64);
        v2 += __shfl_xor(v2, off, 64);
    }
    if (f == 0) { f1[h * S + row] = v1; f2[h * S + row] = v2; }
}

// ---------------------------------------------------------------------------
// Kernel 2: partial column sums Dpart[ic,h,j] = sum_{i in chunk ic} adj[i,j] *
//           exp(lrelu(f1[h,i] + f2[h,j])).  All 8 heads share one adj read.
// grid (S/64 j-tiles, S/256 i-chunks), block 256 (jl = t&63, ig = t>>6).
// ---------------------------------------------------------------------------
__global__ __launch_bounds__(256) void k_colsum(const int* __restrict__ adj,
                                                const float* __restrict__ f1,
                                                const float* __restrict__ f2,
                                                float* __restrict__ Dpart) {
    __shared__ float sf1[H][256];
    __shared__ float red[4][H][64];
    const int j0    = blockIdx.x * 64;
    const int ibase = blockIdx.y * 256;
    const int t  = threadIdx.x;
    const int jl = t & 63, ig = t >> 6;
    for (int idx = t; idx < H * 256; idx += 256) {
        const int hh = idx >> 8, il = idx & 255;
        sf1[hh][il] = f1[hh * S + ibase + il];
    }
    __syncthreads();
    float f2v[H], Dl[H];
#pragma unroll
    for (int hh = 0; hh < H; ++hh) {
        f2v[hh] = f2[hh * S + j0 + jl];
        Dl[hh]  = 0.f;
    }
    for (int s = 0; s < 64; ++s) {
        const int il = ig + 4 * s;
        const float av = (float)adj[(ibase + il) * S + j0 + jl];
#pragma unroll
        for (int hh = 0; hh < H; ++hh) {
            const float e  = sf1[hh][il] + f2v[hh];
            const float lr = e > 0.f ? e : ALPHA * e;
            Dl[hh] += av * __expf(lr);
        }
    }
#pragma unroll
    for (int hh = 0; hh < H; ++hh) red[ig][hh][jl] = Dl[hh];
    __syncthreads();
    if (ig == 0) {
#pragma unroll
        for (int hh = 0; hh < H; ++hh) {
            const float sum = red[0][hh][jl] + red[1][hh][jl] +
                              red[2][hh][jl] + red[3][hh][jl];
            Dpart[(blockIdx.y * H + hh) * S + j0 + jl] = sum;
        }
    }
}

// ---------------------------------------------------------------------------
// Kernel 2b: w[h,j] = 1 / sum_ic Dpart[ic,h,j]
// ---------------------------------------------------------------------------
__global__ __launch_bounds__(256) void k_winv(const float* __restrict__ Dpart,
                                              float* __restrict__ w) {
    const int idx = blockIdx.x * 256 + threadIdx.x;  // over H*S
    float s = 0.f;
#pragma unroll
    for (int c = 0; c < 16; ++c) s += Dpart[c * (H * S) + idx];
    w[idx] = 1.0f / s;
}

// ---------------------------------------------------------------------------
// Kernel 3: out[i, h*64+f] = elu( sum_j P[i,j] * h[h,j,f] ),
//           P[i,j] = adj[i,j] * exp(lrelu(f1[i]+f2[j])) * w[j]  (on the fly).
// grid (S/64 i-tiles, H), block 256. 64x64 block tile, 4x4 per-thread tile.
// LDS: Pt[64][65] (pad -> conflict-free b32 col reads), hsT[64][64].
// ---------------------------------------------------------------------------
__global__ __launch_bounds__(256) void k_attn_out(const int* __restrict__ adj,
                                                  const float* __restrict__ f1,
                                                  const float* __restrict__ f2,
                                                  const float* __restrict__ w,
                                                  const float* __restrict__ hbuf,
                                                  float* __restrict__ out) {
    __shared__ float Pt[64][65];
    __shared__ float hsT[64][64];
    __shared__ float f1s[64];
    const int h  = blockIdx.y;
    const int i0 = blockIdx.x * 64;
    const int t  = threadIdx.x;
    const int jlA = t & 63, igA = t >> 6;  // phase A: lane = column (coalesced adj)
    const int fg  = t & 15, ig = t >> 4;   // phase B: 4x4 tile at (ig*4, fg*4)
    if (t < 64) f1s[t] = f1[h * S + i0 + t];
    float acc[4][4] = {{0.f, 0.f, 0.f, 0.f}, {0.f, 0.f, 0.f, 0.f},
                       {0.f, 0.f, 0.f, 0.f}, {0.f, 0.f, 0.f, 0.f}};
    __syncthreads();
    for (int j0 = 0; j0 < S; j0 += 64) {
        // ---- phase A: P tile + h tile into LDS ----
        const float f2j = f2[h * S + j0 + jlA];
        const float wj  = w[h * S + j0 + jlA];
#pragma unroll
        for (int k = 0; k < 16; ++k) {
            const int il = igA + 4 * k;
            const float av = (float)adj[(i0 + il) * S + j0 + jlA];
            const float e  = f1s[il] + f2j;
            const float lr = e > 0.f ? e : ALPHA * e;
            Pt[il][jlA] = av * __expf(lr) * wj;
        }
#pragma unroll
        for (int k = 0; k < 4; ++k) {
            const int jj = (t >> 4) + k * 16;
            const int f0 = (t & 15) * 4;
            *(float4*)&hsT[jj][f0] =
                *(const float4*)&hbuf[((h * S) + j0 + jj) * FOUT + f0];
        }
        __syncthreads();
        // ---- phase B: 4x4 register-tile FMA over 64 j's ----
#pragma unroll 8
        for (int jl = 0; jl < 64; ++jl) {
            const float4 hv = *(const float4*)&hsT[jl][fg * 4];
            const float p0 = Pt[ig * 4 + 0][jl];
            const float p1 = Pt[ig * 4 + 1][jl];
            const float p2 = Pt[ig * 4 + 2][jl];
            const float p3 = Pt[ig * 4 + 3][jl];
            acc[0][0] += p0 * hv.x; acc[0][1] += p0 * hv.y;
            acc[0][2] += p0 * hv.z; acc[0][3] += p0 * hv.w;
            acc[1][0] += p1 * hv.x; acc[1][1] += p1 * hv.y;
            acc[1][2] += p1 * hv.z; acc[1][3] += p1 * hv.w;
            acc[2][0] += p2 * hv.x; acc[2][1] += p2 * hv.y;
            acc[2][2] += p2 * hv.z; acc[2][3] += p2 * hv.w;
            acc[3][0] += p3 * hv.x; acc[3][1] += p3 * hv.y;
            acc[3][2] += p3 * hv.z; acc[3][3] += p3 * hv.w;
        }
        __syncthreads();
    }
    // ---- epilogue: ELU + transpose-store to [S, H*FOUT] ----
    const int f0 = fg * 4;
#pragma unroll
    for (int r = 0; r < 4; ++r) {
        const int row = i0 + ig * 4 + r;
        float4 o;
        o.x = acc[r][0] > 0.f ? acc[r][0] : __expf(acc[r][0]) - 1.f;
        o.y = acc[r][1] > 0.f ? acc[r][1] : __expf(acc[r][1]) - 1.f;
        o.z = acc[r][2] > 0.f ? acc[r][2] : __expf(acc[r][2]) - 1.f;
        o.w = acc[r][3] > 0.f ? acc[r][3] : __expf(acc[r][3]) - 1.f;
        *(float4*)&out[row * (H * FOUT) + h * FOUT + f0] = o;
    }
}

extern "C" void kernel_launch(void* const* d_in, const int* in_sizes, int n_in,
                              void* d_out, int out_size, void* d_ws, size_t ws_size,
                              hipStream_t stream) {
    const float* X   = (const float*)d_in[0];  // [1,4096,128]
    const int*   adj = (const int*)d_in[1];    // [1,4096,4096]
    const float* W   = (const float*)d_in[2];  // [8,128,64]
    const float* a1  = (const float*)d_in[3];  // [8,64,1]
    const float* a2  = (const float*)d_in[4];  // [8,64,1]
    float* out = (float*)d_out;                // [4096, 512]

    float* ws    = (float*)d_ws;
    float* hbuf  = ws;                    // H*S*FOUT      = 2097152 floats
    float* f1    = hbuf + H * S * FOUT;   // H*S           =   32768
    float* f2    = f1 + H * S;            // H*S           =   32768
    float* Dpart = f2 + H * S;             // 16*H*S        =  524288
    float* winv  = Dpart + 16 * H * S;     // H*S           =   32768
    // total ~10.4 MB of d_ws

    k_proj<<<dim3(S / 4, H), 256, 0, stream>>>(X, W, a1, a2, hbuf, f1, f2);
    k_colsum<<<dim3(S / 64, S / 256), 256, 0, stream>>>(adj, f1, f2, Dpart);
    k_winv<<<dim3(H * S / 256), 256, 0, stream>>>(Dpart, winv);
    k_attn_out<<<dim3(S / 64, H), 256, 0, stream>>>(adj, f1, f2, winv, hbuf, out);
}

// Round 2
// 223.624 us; speedup vs baseline: 1.9945x; 1.9945x over previous
//
#include <hip/hip_runtime.h>

#define S 4096
#define FIN 128
#define FOUT 64
#define H 8
#define ALPHA 0.2f

typedef __attribute__((ext_vector_type(8))) short bf16x8;
typedef __attribute__((ext_vector_type(4))) float f32x4;

__device__ __forceinline__ unsigned short f2bf(float x) {
    unsigned int u = __builtin_bit_cast(unsigned int, x);
    u += 0x7fffu + ((u >> 16) & 1u);  // round-to-nearest-even
    return (unsigned short)(u >> 16);
}

// ---------------------------------------------------------------------------
// k_proj: h = X·W (fp32 accum), store hT[h][f][j] as bf16 (transposed for MFMA
// B-fragments); f1 = h·a1, f2 = h·a2 in fp32.
// grid (S/64, H), 256 threads; 4x4 register tile, K staged in 32-chunks.
// ---------------------------------------------------------------------------
__global__ __launch_bounds__(256) void k_proj(const float* __restrict__ X,
                                              const float* __restrict__ W,
                                              const float* __restrict__ a1,
                                              const float* __restrict__ a2,
                                              unsigned short* __restrict__ hT,
                                              float* __restrict__ f1,
                                              float* __restrict__ f2) {
    __shared__ float xs[64][36];   // [row j][k-chunk 32] pad->16B-aligned rows
    __shared__ float Ws[32][68];   // [k][f 64]
    const int h  = blockIdx.y;
    const int j0 = blockIdx.x * 64;
    const int t  = threadIdx.x;
    const int fg = t & 15, rg = t >> 4;   // compute: 4 f at fg*4, 4 rows at rg*4
    const int jr = t >> 2, q = t & 3;     // X loader
    const int kw = t >> 3, cw = t & 7;    // W loader
    float acc[4][4] = {};
#pragma unroll
    for (int k0 = 0; k0 < FIN; k0 += 32) {
        *(float4*)&xs[jr][q * 8]     = *(const float4*)&X[(j0 + jr) * FIN + k0 + q * 8];
        *(float4*)&xs[jr][q * 8 + 4] = *(const float4*)&X[(j0 + jr) * FIN + k0 + q * 8 + 4];
        *(float4*)&Ws[kw][cw * 8]     = *(const float4*)&W[(h * FIN + k0 + kw) * FOUT + cw * 8];
        *(float4*)&Ws[kw][cw * 8 + 4] = *(const float4*)&W[(h * FIN + k0 + kw) * FOUT + cw * 8 + 4];
        __syncthreads();
#pragma unroll
        for (int kc = 0; kc < 8; ++kc) {
            float4 xr[4], wr[4];
#pragma unroll
            for (int r = 0; r < 4; ++r) xr[r] = *(const float4*)&xs[4 * rg + r][kc * 4];
#pragma unroll
            for (int kk = 0; kk < 4; ++kk) wr[kk] = *(const float4*)&Ws[kc * 4 + kk][fg * 4];
#pragma unroll
            for (int r = 0; r < 4; ++r) {
                const float* xp = (const float*)&xr[r];
#pragma unroll
                for (int kk = 0; kk < 4; ++kk) {
                    const float xv = xp[kk];
                    acc[r][0] += xv * wr[kk].x;
                    acc[r][1] += xv * wr[kk].y;
                    acc[r][2] += xv * wr[kk].z;
                    acc[r][3] += xv * wr[kk].w;
                }
            }
        }
        __syncthreads();
    }
    // f1/f2: partial over this thread's 4 f's, reduce across the 16-lane f-group
    const float4 a1v = *(const float4*)&a1[h * FOUT + fg * 4];
    const float4 a2v = *(const float4*)&a2[h * FOUT + fg * 4];
#pragma unroll
    for (int r = 0; r < 4; ++r) {
        float p1 = acc[r][0] * a1v.x + acc[r][1] * a1v.y + acc[r][2] * a1v.z + acc[r][3] * a1v.w;
        float p2 = acc[r][0] * a2v.x + acc[r][1] * a2v.y + acc[r][2] * a2v.z + acc[r][3] * a2v.w;
#pragma unroll
        for (int off = 1; off < 16; off <<= 1) {
            p1 += __shfl_xor(p1, off, 64);
            p2 += __shfl_xor(p2, off, 64);
        }
        if (fg == 0) {
            f1[h * S + j0 + 4 * rg + r] = p1;
            f2[h * S + j0 + 4 * rg + r] = p2;
        }
    }
    // hT store: 4 consecutive j's per f-row, packed bf16 (8B stores)
#pragma unroll
    for (int c = 0; c < 4; ++c) {
        ushort4 pk;
        pk.x = f2bf(acc[0][c]);
        pk.y = f2bf(acc[1][c]);
        pk.z = f2bf(acc[2][c]);
        pk.w = f2bf(acc[3][c]);
        *(ushort4*)&hT[(h * FOUT + fg * 4 + c) * S + j0 + 4 * rg] = pk;
    }
}

// ---------------------------------------------------------------------------
// k_colsum: Dpart[ic,h,j] = sum_{i in chunk} adj(i,j)*exp(lrelu(f1[h,i]+f2[h,j]))
// AND packs adj into the 2MB bitmask bm (ballot: wave lanes == 64 j's of row i).
// grid (S/64 j-tiles, S/256 i-chunks), 256 threads.
// ---------------------------------------------------------------------------
__global__ __launch_bounds__(256) void k_colsum(const int* __restrict__ adj,
                                                const float* __restrict__ f1,
                                                const float* __restrict__ f2,
                                                float* __restrict__ Dpart,
                                                unsigned int* __restrict__ bm) {
    __shared__ float sf1[H][256];
    __shared__ float red[4][H][64];
    const int j0    = blockIdx.x * 64;
    const int ibase = blockIdx.y * 256;
    const int t  = threadIdx.x;
    const int jl = t & 63, ig = t >> 6;
    for (int idx = t; idx < H * 256; idx += 256)
        sf1[idx >> 8][idx & 255] = f1[(idx >> 8) * S + ibase + (idx & 255)];
    __syncthreads();
    float f2v[H], Dl[H];
#pragma unroll
    for (int hh = 0; hh < H; ++hh) { f2v[hh] = f2[hh * S + j0 + jl]; Dl[hh] = 0.f; }
    for (int s = 0; s < 64; ++s) {
        const int il  = ig + 4 * s;
        const int row = ibase + il;
        const int pred = adj[row * S + j0 + jl] != 0;
        const unsigned long long m = __ballot(pred);
        if ((jl & 31) == 0)
            bm[row * (S / 32) + (j0 >> 5) + (jl >> 5)] = (unsigned int)(m >> jl);
        const float bitf = (float)pred;
#pragma unroll
        for (int hh = 0; hh < H; ++hh) {
            const float e = sf1[hh][il] + f2v[hh];
            Dl[hh] += bitf * __expf(fmaxf(e, ALPHA * e));
        }
    }
#pragma unroll
    for (int hh = 0; hh < H; ++hh) red[ig][hh][jl] = Dl[hh];
    __syncthreads();
    if (ig == 0) {
#pragma unroll
        for (int hh = 0; hh < H; ++hh) {
            const float sum = red[0][hh][jl] + red[1][hh][jl] +
                              red[2][hh][jl] + red[3][hh][jl];
            Dpart[(blockIdx.y * H + hh) * S + j0 + jl] = sum;
        }
    }
}

// ---------------------------------------------------------------------------
// k_finish: wf2[h,j] = (f2[h,j], 1/sum_ic Dpart[ic,h,j])  — one load in k_attn
// ---------------------------------------------------------------------------
__global__ __launch_bounds__(256) void k_finish(const float* __restrict__ Dpart,
                                                const float* __restrict__ f2,
                                                float2* __restrict__ wf2) {
    const int idx = blockIdx.x * 256 + threadIdx.x;  // over H*S
    float s = 0.f;
#pragma unroll
    for (int c = 0; c < 16; ++c) s += Dpart[c * (H * S) + idx];
    wf2[idx] = make_float2(f2[idx], 1.0f / s);
}

// ---------------------------------------------------------------------------
// k_attn: out[i, h*64+f] = elu( sum_j P[i,j]*hT[h][f][j] ), MFMA 16x16x32 bf16.
// P built on the fly from bitmask+f1+f2+w, packed bf16 into A-layout LDS.
// grid (S/64, H), 512 threads = 8 waves; wave tile 16(M) x 32(N); K-tile 64.
// LDS rows padded 64->72 (stride 144B): A/B b128 frag reads are 2-way = free.
// ---------------------------------------------------------------------------
__global__ __launch_bounds__(512) void k_attn(const unsigned int* __restrict__ bm,
                                              const float* __restrict__ f1,
                                              const float2* __restrict__ wf2,
                                              const unsigned short* __restrict__ hT,
                                              float* __restrict__ out) {
    __shared__ unsigned short Pt[64][72];  // [i-local][j-local]  (A: M x K)
    __shared__ unsigned short Bs[64][72];  // [f][j-local]        (B^T: N x K)
    const int h  = blockIdx.y;
    const int i0 = blockIdx.x * 64;
    const int t  = threadIdx.x;
    const int jp = t & 31, rr = t >> 5;      // phase A: j = 2jp,2jp+1; rows rr+16k
    const int fr = t >> 3, cb = t & 7;       // B-tile loader: f-row, 16B chunk
    const int lane = t & 63, w = t >> 6;
    const int mrow = (w >> 1) * 16, ncol = (w & 1) * 32;
    const int am = lane & 15, kg = lane >> 4;

    float f1r[4];
#pragma unroll
    for (int k = 0; k < 4; ++k) f1r[k] = f1[h * S + i0 + rr + 16 * k];

    f32x4 acc0 = {0.f, 0.f, 0.f, 0.f};
    f32x4 acc1 = {0.f, 0.f, 0.f, 0.f};

    const float2*         wp  = wf2 + h * S + 2 * jp;
    const unsigned short* hp  = hT + (h * FOUT + fr) * S + cb * 8;
    const unsigned int*   bmp = bm + i0 * (S / 32) + (jp >> 4);
    const int sh0 = (2 * jp) & 31;

    for (int j0 = 0; j0 < S; j0 += 64) {
        const float2 fw0 = wp[0];
        const float2 fw1 = wp[1];
        wp += 64;
        // ---- B tile: hT[h][0:64][j0:j0+64] -> Bs (16B per thread) ----
        *(uint4*)&Bs[fr][cb * 8] = *(const uint4*)&hp[j0];
        // ---- P tile: 4 rows x 2 j's per thread, packed bf16 b32 stores ----
#pragma unroll
        for (int k = 0; k < 4; ++k) {
            const int il = rr + 16 * k;
            const unsigned int wrd = bmp[il * (S / 32) + (j0 >> 5)];
            const float e0 = f1r[k] + fw0.x;
            const float e1 = f1r[k] + fw1.x;
            float v0 = __expf(fmaxf(e0, ALPHA * e0)) * fw0.y;
            float v1 = __expf(fmaxf(e1, ALPHA * e1)) * fw1.y;
            v0 = ((wrd >> sh0) & 1u) ? v0 : 0.f;
            v1 = ((wrd >> sh0) & 2u) ? v1 : 0.f;
            *(unsigned int*)&Pt[il][2 * jp] =
                (unsigned int)f2bf(v0) | ((unsigned int)f2bf(v1) << 16);
        }
        __syncthreads();
        // ---- MFMA: A lane holds A[m=lane&15][k=kg*8+jj]; B lane B[k][n=lane&15]
#pragma unroll
        for (int kc = 0; kc < 2; ++kc) {
            const int koff = kc * 32 + kg * 8;
            const bf16x8 a  = *(const bf16x8*)&Pt[mrow + am][koff];
            const bf16x8 b0 = *(const bf16x8*)&Bs[ncol + am][koff];
            const bf16x8 b1 = *(const bf16x8*)&Bs[ncol + 16 + am][koff];
            acc0 = __builtin_amdgcn_mfma_f32_16x16x32_bf16(a, b0, acc0, 0, 0, 0);
            acc1 = __builtin_amdgcn_mfma_f32_16x16x32_bf16(a, b1, acc1, 0, 0, 0);
        }
        __syncthreads();
    }
    // epilogue: D row=(lane>>4)*4+r, col=lane&15 ; ELU ; coalesced-ish 64B runs
#pragma unroll
    for (int r = 0; r < 4; ++r) {
        const int i  = i0 + mrow + kg * 4 + r;
        const float x0 = acc0[r], x1 = acc1[r];
        out[i * (H * FOUT) + h * FOUT + ncol + am]      = x0 > 0.f ? x0 : __expf(x0) - 1.f;
        out[i * (H * FOUT) + h * FOUT + ncol + 16 + am] = x1 > 0.f ? x1 : __expf(x1) - 1.f;
    }
}

extern "C" void kernel_launch(void* const* d_in, const int* in_sizes, int n_in,
                              void* d_out, int out_size, void* d_ws, size_t ws_size,
                              hipStream_t stream) {
    const float* X   = (const float*)d_in[0];  // [1,4096,128]
    const int*   adj = (const int*)d_in[1];    // [1,4096,4096]
    const float* W   = (const float*)d_in[2];  // [8,128,64]
    const float* a1  = (const float*)d_in[3];  // [8,64,1]
    const float* a2  = (const float*)d_in[4];  // [8,64,1]
    float* out = (float*)d_out;                // [4096, 512]

    char* ws = (char*)d_ws;
    unsigned short* hT = (unsigned short*)ws;            // H*FOUT*S bf16 = 4 MB
    float*  f1    = (float*)(ws + 4 * 1024 * 1024);      // H*S = 128 KB
    float*  f2    = f1 + H * S;                          // 128 KB
    float*  Dpart = f2 + H * S;                          // 16*H*S = 2 MB
    float2* wf2   = (float2*)(Dpart + 16 * H * S);       // 256 KB
    unsigned int* bm = (unsigned int*)(wf2 + H * S);     // S*S/32 = 2 MB
    // total ~8.6 MB of d_ws

    k_proj  <<<dim3(S / 64, H),      256, 0, stream>>>(X, W, a1, a2, hT, f1, f2);
    k_colsum<<<dim3(S / 64, S / 256), 256, 0, stream>>>(adj, f1, f2, Dpart, bm);
    k_finish<<<dim3(H * S / 256),    256, 0, stream>>>(Dpart, f2, wf2);
    k_attn  <<<dim3(S / 64, H),      512, 0, stream>>>(bm, f1, wf2, hT, out);
}

// Round 3
// 220.586 us; speedup vs baseline: 2.0220x; 1.0138x over previous
//
#include <hip/hip_runtime.h>

#define S 4096
#define FIN 128
#define FOUT 64
#define H 8
#define ALPHA 0.2f

typedef __attribute__((ext_vector_type(8)))  short bf16x8;
typedef __attribute__((ext_vector_type(16))) float f32x16;

__device__ __forceinline__ unsigned short f2bf(float x) {
    unsigned int u = __builtin_bit_cast(unsigned int, x);
    u += 0x7fffu + ((u >> 16) & 1u);  // RTNE
    return (unsigned short)(u >> 16);
}

// ---------------------------------------------------------------------------
// k_proj: h = X·W (fp32), hT[h][f][j] bf16 (transposed for B-frags);
// f1=h·a1, f2=h·a2 -> store exp-pairs E1=(e^f1, e^{a f1}), E2=(e^f2, e^{a f2}).
// ---------------------------------------------------------------------------
__global__ __launch_bounds__(256) void k_proj(const float* __restrict__ X,
                                              const float* __restrict__ W,
                                              const float* __restrict__ a1,
                                              const float* __restrict__ a2,
                                              unsigned short* __restrict__ hT,
                                              float2* __restrict__ E1p,
                                              float2* __restrict__ E2p) {
    __shared__ float xs[64][36];
    __shared__ float Ws[32][68];
    const int h  = blockIdx.y;
    const int j0 = blockIdx.x * 64;
    const int t  = threadIdx.x;
    const int fg = t & 15, rg = t >> 4;
    const int jr = t >> 2, q = t & 3;
    const int kw = t >> 3, cw = t & 7;
    float acc[4][4] = {};
#pragma unroll
    for (int k0 = 0; k0 < FIN; k0 += 32) {
        *(float4*)&xs[jr][q * 8]      = *(const float4*)&X[(j0 + jr) * FIN + k0 + q * 8];
        *(float4*)&xs[jr][q * 8 + 4]  = *(const float4*)&X[(j0 + jr) * FIN + k0 + q * 8 + 4];
        *(float4*)&Ws[kw][cw * 8]     = *(const float4*)&W[(h * FIN + k0 + kw) * FOUT + cw * 8];
        *(float4*)&Ws[kw][cw * 8 + 4] = *(const float4*)&W[(h * FIN + k0 + kw) * FOUT + cw * 8 + 4];
        __syncthreads();
#pragma unroll
        for (int kc = 0; kc < 8; ++kc) {
            float4 xr[4], wr[4];
#pragma unroll
            for (int r = 0; r < 4; ++r) xr[r] = *(const float4*)&xs[4 * rg + r][kc * 4];
#pragma unroll
            for (int kk = 0; kk < 4; ++kk) wr[kk] = *(const float4*)&Ws[kc * 4 + kk][fg * 4];
#pragma unroll
            for (int r = 0; r < 4; ++r) {
                const float* xp = (const float*)&xr[r];
#pragma unroll
                for (int kk = 0; kk < 4; ++kk) {
                    const float xv = xp[kk];
                    acc[r][0] += xv * wr[kk].x;
                    acc[r][1] += xv * wr[kk].y;
                    acc[r][2] += xv * wr[kk].z;
                    acc[r][3] += xv * wr[kk].w;
                }
            }
        }
        __syncthreads();
    }
    const float4 a1v = *(const float4*)&a1[h * FOUT + fg * 4];
    const float4 a2v = *(const float4*)&a2[h * FOUT + fg * 4];
#pragma unroll
    for (int r = 0; r < 4; ++r) {
        float p1 = acc[r][0] * a1v.x + acc[r][1] * a1v.y + acc[r][2] * a1v.z + acc[r][3] * a1v.w;
        float p2 = acc[r][0] * a2v.x + acc[r][1] * a2v.y + acc[r][2] * a2v.z + acc[r][3] * a2v.w;
#pragma unroll
        for (int off = 1; off < 16; off <<= 1) {
            p1 += __shfl_xor(p1, off, 64);
            p2 += __shfl_xor(p2, off, 64);
        }
        if (fg == 0) {
            const int row = j0 + 4 * rg + r;
            E1p[h * S + row] = make_float2(__expf(p1), __expf(ALPHA * p1));
            E2p[h * S + row] = make_float2(__expf(p2), __expf(ALPHA * p2));
        }
    }
#pragma unroll
    for (int c = 0; c < 4; ++c) {
        ushort4 pk;
        pk.x = f2bf(acc[0][c]);
        pk.y = f2bf(acc[1][c]);
        pk.z = f2bf(acc[2][c]);
        pk.w = f2bf(acc[3][c]);
        *(ushort4*)&hT[(h * FOUT + fg * 4 + c) * S + j0 + 4 * rg] = pk;
    }
}

// ---------------------------------------------------------------------------
// k_colsum: Dpart[ic,h,j] = sum_i adj(i,j)*max(E1x*E2x, E1y*E2y)  (exp-free)
// + packs adj into bitmask bm via ballot.
// ---------------------------------------------------------------------------
__global__ __launch_bounds__(256) void k_colsum(const int* __restrict__ adj,
                                                const float2* __restrict__ E1p,
                                                const float2* __restrict__ E2p,
                                                float* __restrict__ Dpart,
                                                unsigned int* __restrict__ bm) {
    __shared__ float2 sE1[H][256];
    __shared__ float red[4][H][64];
    const int j0    = blockIdx.x * 64;
    const int ibase = blockIdx.y * 256;
    const int t  = threadIdx.x;
    const int jl = t & 63, ig = t >> 6;
    for (int idx = t; idx < 1024; idx += 256) {
        const int hh = idx >> 7, pos = idx & 127;
        *(float4*)&sE1[hh][pos * 2] = *(const float4*)&E1p[hh * S + ibase + pos * 2];
    }
    __syncthreads();
    float2 e2v[H];
    float Dl[H];
#pragma unroll
    for (int hh = 0; hh < H; ++hh) { e2v[hh] = E2p[hh * S + j0 + jl]; Dl[hh] = 0.f; }
    for (int s = 0; s < 64; ++s) {
        const int il  = ig + 4 * s;
        const int row = ibase + il;
        const int pred = adj[row * S + j0 + jl] != 0;
        const unsigned long long m = __ballot(pred);
        if ((jl & 31) == 0)
            bm[row * (S / 32) + (j0 >> 5) + (jl >> 5)] = (unsigned int)(m >> jl);
        const float bitf = (float)pred;
#pragma unroll
        for (int hh = 0; hh < H; ++hh) {
            const float2 e1 = sE1[hh][il];
            Dl[hh] += bitf * fmaxf(e1.x * e2v[hh].x, e1.y * e2v[hh].y);
        }
    }
#pragma unroll
    for (int hh = 0; hh < H; ++hh) red[ig][hh][jl] = Dl[hh];
    __syncthreads();
    if (ig == 0) {
#pragma unroll
        for (int hh = 0; hh < H; ++hh) {
            const float sum = red[0][hh][jl] + red[1][hh][jl] +
                              red[2][hh][jl] + red[3][hh][jl];
            Dpart[(blockIdx.y * H + hh) * S + j0 + jl] = sum;
        }
    }
}

// ---------------------------------------------------------------------------
// k_finish: wE2[h,j] = E2pair[h,j] * (1/colsum)  — w folded into the pair
// ---------------------------------------------------------------------------
__global__ __launch_bounds__(256) void k_finish(const float* __restrict__ Dpart,
                                                const float2* __restrict__ E2p,
                                                float2* __restrict__ wE2) {
    const int idx = blockIdx.x * 256 + threadIdx.x;
    float s = 0.f;
#pragma unroll
    for (int c = 0; c < 16; ++c) s += Dpart[c * (H * S) + idx];
    const float w = 1.0f / s;
    const float2 e2 = E2p[idx];
    wE2[idx] = make_float2(e2.x * w, e2.y * w);
}

// ---------------------------------------------------------------------------
// k_attn: O[i, h*64+f] += sum_j P[i,j]*hT[h][f][j]  via mfma_f32_32x32x16_bf16.
// A-fragments (P) built DIRECTLY in registers: lane owns row i = i0+w*32+(lane&31),
// builds 8 bf16 elems per K16-step from (E1 pair const per lane) x (E2w LDS
// broadcast) x (bitmask byte). No P LDS round-trip. Bs XOR-swizzled.
// grid (S/128, H, 2 j-halves); 256 thr = 4 waves (M=4x32, N=64 per wave).
// fp32 atomicAdd partials into pre-zeroed out; k_elu applies ELU after.
// ---------------------------------------------------------------------------
__global__ __launch_bounds__(256) void k_attn(const unsigned int* __restrict__ bm,
                                              const float2* __restrict__ E1p,
                                              const float2* __restrict__ wE2,
                                              const unsigned short* __restrict__ hT,
                                              float* __restrict__ out) {
    __shared__ __align__(16) unsigned short Bs[64 * 64];  // [f][chunk^(f&7)][8]
    __shared__ __align__(16) float2 E2s[64];
    const int h  = blockIdx.y;
    const int i0 = blockIdx.x * 128;
    const int z  = blockIdx.z;
    const int t  = threadIdx.x;
    const int w  = t >> 6, lane = t & 63;
    const int am = lane & 31, kh = lane >> 5;
    const int i  = i0 + w * 32 + am;

    const float2 e1 = E1p[h * S + i];
    const float ea = e1.x, eb = e1.y;

    const int fb = t >> 3, cb = t & 7;  // B loader: row fb (per 32-row chunk), 16B chunk cb

    f32x16 acc0 = {0,0,0,0,0,0,0,0,0,0,0,0,0,0,0,0};
    f32x16 acc1 = {0,0,0,0,0,0,0,0,0,0,0,0,0,0,0,0};

    const unsigned int* bmrow = bm + i * (S / 32);
    const int jbase = z * (S / 2);

    for (int jt = 0; jt < 32; ++jt) {
        const int j0 = jbase + jt * 64;
        __syncthreads();
        if (t < 32)
            *(float4*)&E2s[t * 2] = *(const float4*)&wE2[h * S + j0 + t * 2];
#pragma unroll
        for (int c = 0; c < 2; ++c) {
            const int f = c * 32 + fb;
            const uint4 v = *(const uint4*)&hT[(h * FOUT + f) * S + j0 + cb * 8];
            *(uint4*)&Bs[f * 64 + ((cb ^ (f & 7)) * 8)] = v;
        }
        const uint2 mrow = *(const uint2*)&bmrow[j0 >> 5];
        __syncthreads();
#pragma unroll
        for (int s = 0; s < 4; ++s) {
            const int p = s * 16 + kh * 8;
            const unsigned int byte = ((p < 32 ? mrow.x : mrow.y) >> (p & 31)) & 0xffu;
            const float4 q01 = *(const float4*)&E2s[s * 16 + kh * 8 + 0];
            const float4 q23 = *(const float4*)&E2s[s * 16 + kh * 8 + 2];
            const float4 q45 = *(const float4*)&E2s[s * 16 + kh * 8 + 4];
            const float4 q67 = *(const float4*)&E2s[s * 16 + kh * 8 + 6];
            float v[8];
            v[0] = fmaxf(ea * q01.x, eb * q01.y);
            v[1] = fmaxf(ea * q01.z, eb * q01.w);
            v[2] = fmaxf(ea * q23.x, eb * q23.y);
            v[3] = fmaxf(ea * q23.z, eb * q23.w);
            v[4] = fmaxf(ea * q45.x, eb * q45.y);
            v[5] = fmaxf(ea * q45.z, eb * q45.w);
            v[6] = fmaxf(ea * q67.x, eb * q67.y);
            v[7] = fmaxf(ea * q67.z, eb * q67.w);
            unsigned int u[8];
#pragma unroll
            for (int jj = 0; jj < 8; ++jj) {
                const float vm = ((byte >> jj) & 1u) ? v[jj] : 0.f;
                u[jj] = __builtin_bit_cast(unsigned int, vm) + 0x8000u;  // round-half-up
            }
            int4 aw;
            aw.x = (int)__builtin_amdgcn_perm(u[1], u[0], 0x07060302u);
            aw.y = (int)__builtin_amdgcn_perm(u[3], u[2], 0x07060302u);
            aw.z = (int)__builtin_amdgcn_perm(u[5], u[4], 0x07060302u);
            aw.w = (int)__builtin_amdgcn_perm(u[7], u[6], 0x07060302u);
            const bf16x8 af = __builtin_bit_cast(bf16x8, aw);
            const int chunk = s * 2 + kh;
            const bf16x8 b0 = *(const bf16x8*)&Bs[am * 64 + ((chunk ^ (am & 7)) * 8)];
            const bf16x8 b1 = *(const bf16x8*)&Bs[(am + 32) * 64 + ((chunk ^ ((am + 32) & 7)) * 8)];
            acc0 = __builtin_amdgcn_mfma_f32_32x32x16_bf16(af, b0, acc0, 0, 0, 0);
            acc1 = __builtin_amdgcn_mfma_f32_32x32x16_bf16(af, b1, acc1, 0, 0, 0);
        }
    }
    // C layout (32x32): col = lane&31, row = (reg&3) + 8*(reg>>2) + 4*(lane>>5)
#pragma unroll
    for (int r = 0; r < 16; ++r) {
        const int il  = (r & 3) + 8 * (r >> 2) + 4 * kh;
        const int row = i0 + w * 32 + il;
        atomicAdd(&out[row * (H * FOUT) + h * FOUT + am],      acc0[r]);
        atomicAdd(&out[row * (H * FOUT) + h * FOUT + 32 + am], acc1[r]);
    }
}

// ---------------------------------------------------------------------------
// k_elu: in-place ELU over out (after both j-halves accumulated)
// ---------------------------------------------------------------------------
__global__ __launch_bounds__(256) void k_elu(float* __restrict__ out) {
    const int idx = (blockIdx.x * 256 + threadIdx.x) * 4;
    float4 v = *(float4*)&out[idx];
    v.x = v.x > 0.f ? v.x : __expf(v.x) - 1.f;
    v.y = v.y > 0.f ? v.y : __expf(v.y) - 1.f;
    v.z = v.z > 0.f ? v.z : __expf(v.z) - 1.f;
    v.w = v.w > 0.f ? v.w : __expf(v.w) - 1.f;
    *(float4*)&out[idx] = v;
}

extern "C" void kernel_launch(void* const* d_in, const int* in_sizes, int n_in,
                              void* d_out, int out_size, void* d_ws, size_t ws_size,
                              hipStream_t stream) {
    const float* X   = (const float*)d_in[0];  // [1,4096,128]
    const int*   adj = (const int*)d_in[1];    // [1,4096,4096]
    const float* W   = (const float*)d_in[2];  // [8,128,64]
    const float* a1  = (const float*)d_in[3];  // [8,64,1]
    const float* a2  = (const float*)d_in[4];  // [8,64,1]
    float* out = (float*)d_out;                // [4096, 512]

    char* ws = (char*)d_ws;
    unsigned short* hT = (unsigned short*)ws;                       // 4 MB
    float2* E1p   = (float2*)(ws + (4u << 20));                     // 512 KB
    float2* E2p   = (float2*)(ws + (4u << 20) + (512u << 10));      // 512 KB
    float*  Dpart = (float*)(ws + (5u << 20));                      // 2 MB
    float2* wE2   = (float2*)(ws + (7u << 20));                     // 512 KB
    unsigned int* bm = (unsigned int*)(ws + (7u << 20) + (512u << 10));  // 2 MB
    // total 9.5 MB

    hipMemsetAsync(out, 0, (size_t)out_size * sizeof(float), stream);
    k_proj  <<<dim3(S / 64, H),       256, 0, stream>>>(X, W, a1, a2, hT, E1p, E2p);
    k_colsum<<<dim3(S / 64, S / 256), 256, 0, stream>>>(adj, E1p, E2p, Dpart, bm);
    k_finish<<<dim3(H * S / 256),     256, 0, stream>>>(Dpart, E2p, wE2);
    k_attn  <<<dim3(S / 128, H, 2),   256, 0, stream>>>(bm, E1p, wE2, hT, out);
    k_elu   <<<dim3(out_size / 1024), 256, 0, stream>>>(out);
}

// Round 5
// 211.468 us; speedup vs baseline: 2.1092x; 1.0431x over previous
//
#include <hip/hip_runtime.h>

#define S 4096
#define FIN 128
#define FOUT 64
#define H 8
#define ALPHA 0.2f

typedef __attribute__((ext_vector_type(2)))  _Float16 f16x2;
typedef __attribute__((ext_vector_type(8)))  _Float16 f16x8;
typedef __attribute__((ext_vector_type(16))) float    f32x16;

__device__ __forceinline__ unsigned short f2h(float x) {
    return __builtin_bit_cast(unsigned short, (_Float16)x);  // RTNE
}

// ---------------------------------------------------------------------------
// k_proj: h = X·W (fp32), hT[h][f][j] fp16 (transposed for B-frags);
// f1=h·a1, f2=h·a2 -> E1h[i][h]=(e^f1,e^{a f1}) (head-interleaved, 64B/row,
// for k_colsum scalar loads); E2p[h][j]=(e^f2,e^{a f2}).
// ---------------------------------------------------------------------------
__global__ __launch_bounds__(256) void k_proj(const float* __restrict__ X,
                                              const float* __restrict__ W,
                                              const float* __restrict__ a1,
                                              const float* __restrict__ a2,
                                              unsigned short* __restrict__ hT,
                                              float2* __restrict__ E1h,
                                              float2* __restrict__ E2p) {
    __shared__ float xs[64][36];
    __shared__ float Ws[32][68];
    const int h  = blockIdx.y;
    const int j0 = blockIdx.x * 64;
    const int t  = threadIdx.x;
    const int fg = t & 15, rg = t >> 4;
    const int jr = t >> 2, q = t & 3;
    const int kw = t >> 3, cw = t & 7;
    float acc[4][4] = {};
#pragma unroll
    for (int k0 = 0; k0 < FIN; k0 += 32) {
        *(float4*)&xs[jr][q * 8]      = *(const float4*)&X[(j0 + jr) * FIN + k0 + q * 8];
        *(float4*)&xs[jr][q * 8 + 4]  = *(const float4*)&X[(j0 + jr) * FIN + k0 + q * 8 + 4];
        *(float4*)&Ws[kw][cw * 8]     = *(const float4*)&W[(h * FIN + k0 + kw) * FOUT + cw * 8];
        *(float4*)&Ws[kw][cw * 8 + 4] = *(const float4*)&W[(h * FIN + k0 + kw) * FOUT + cw * 8 + 4];
        __syncthreads();
#pragma unroll
        for (int kc = 0; kc < 8; ++kc) {
            float4 xr[4], wr[4];
#pragma unroll
            for (int r = 0; r < 4; ++r) xr[r] = *(const float4*)&xs[4 * rg + r][kc * 4];
#pragma unroll
            for (int kk = 0; kk < 4; ++kk) wr[kk] = *(const float4*)&Ws[kc * 4 + kk][fg * 4];
#pragma unroll
            for (int r = 0; r < 4; ++r) {
                const float* xp = (const float*)&xr[r];
#pragma unroll
                for (int kk = 0; kk < 4; ++kk) {
                    const float xv = xp[kk];
                    acc[r][0] += xv * wr[kk].x;
                    acc[r][1] += xv * wr[kk].y;
                    acc[r][2] += xv * wr[kk].z;
                    acc[r][3] += xv * wr[kk].w;
                }
            }
        }
        __syncthreads();
    }
    const float4 a1v = *(const float4*)&a1[h * FOUT + fg * 4];
    const float4 a2v = *(const float4*)&a2[h * FOUT + fg * 4];
#pragma unroll
    for (int r = 0; r < 4; ++r) {
        float p1 = acc[r][0] * a1v.x + acc[r][1] * a1v.y + acc[r][2] * a1v.z + acc[r][3] * a1v.w;
        float p2 = acc[r][0] * a2v.x + acc[r][1] * a2v.y + acc[r][2] * a2v.z + acc[r][3] * a2v.w;
#pragma unroll
        for (int off = 1; off < 16; off <<= 1) {
            p1 += __shfl_xor(p1, off, 64);
            p2 += __shfl_xor(p2, off, 64);
        }
        if (fg == 0) {
            const int row = j0 + 4 * rg + r;
            E1h[(size_t)row * H + h] = make_float2(__expf(p1), __expf(ALPHA * p1));
            E2p[h * S + row]         = make_float2(__expf(p2), __expf(ALPHA * p2));
        }
    }
#pragma unroll
    for (int c = 0; c < 4; ++c) {
        ushort4 pk;
        pk.x = f2h(acc[0][c]);
        pk.y = f2h(acc[1][c]);
        pk.z = f2h(acc[2][c]);
        pk.w = f2h(acc[3][c]);
        *(ushort4*)&hT[(h * FOUT + fg * 4 + c) * S + j0 + 4 * rg] = pk;
    }
}

// ---------------------------------------------------------------------------
// k_colsum: Dcol[h,j] += sum_i adj(i,j)*max(E1x*E2x, E1y*E2y); packs bm.
// Wave-contiguous rows -> E1h row (64B, all 8 heads) is wave-uniform =>
// scalar s_load; no LDS in the hot loop. grid (S/64, S/256), 256 thr.
// ---------------------------------------------------------------------------
__global__ __launch_bounds__(256) void k_colsum(const int* __restrict__ adj,
                                                const float2* __restrict__ E1h,
                                                const float2* __restrict__ E2p,
                                                float* __restrict__ Dcol,
                                                unsigned int* __restrict__ bm) {
    __shared__ float red[4][H][64];
    const int j0    = blockIdx.x * 64;
    const int ibase = blockIdx.y * 256;
    const int t  = threadIdx.x;
    const int jl = t & 63;
    const int wv = __builtin_amdgcn_readfirstlane(t >> 6);
    float2 e2v[H];
    float Dl[H];
#pragma unroll
    for (int hh = 0; hh < H; ++hh) { e2v[hh] = E2p[hh * S + j0 + jl]; Dl[hh] = 0.f; }
    const int rowbase = ibase + wv * 64;
    for (int s = 0; s < 64; ++s) {
        const int row = rowbase + s;
        const float2* __restrict__ e1r = E1h + (size_t)row * H;  // wave-uniform
        const int av = adj[(size_t)row * S + j0 + jl];
        const unsigned long long blt = __ballot(av != 0);
        if (jl == 0)
            *(uint2*)&bm[row * (S / 32) + (j0 >> 5)] =
                make_uint2((unsigned int)blt, (unsigned int)(blt >> 32));
        const float bf = av != 0 ? 1.f : 0.f;
#pragma unroll
        for (int hh = 0; hh < H; ++hh) {
            const float2 e1 = e1r[hh];
            Dl[hh] = fmaf(bf, fmaxf(e1.x * e2v[hh].x, e1.y * e2v[hh].y), Dl[hh]);
        }
    }
#pragma unroll
    for (int hh = 0; hh < H; ++hh) red[wv][hh][jl] = Dl[hh];
    __syncthreads();
    if (wv == 0) {
#pragma unroll
        for (int hh = 0; hh < H; ++hh) {
            const float sum = red[0][hh][jl] + red[1][hh][jl] +
                              red[2][hh][jl] + red[3][hh][jl];
            atomicAdd(&Dcol[hh * S + j0 + jl], sum);
        }
    }
}

// ---------------------------------------------------------------------------
// k_finish: wE2h[h][jpair] = { h2(qx_j,qx_j1), h2(qy_j,qy_j1) },
// q = E2pair / colsum  (w folded in, packed fp16 SoA pairs for k_attn)
// ---------------------------------------------------------------------------
__global__ __launch_bounds__(256) void k_finish(const float* __restrict__ Dcol,
                                                const float2* __restrict__ E2p,
                                                uint2* __restrict__ wE2h) {
    const int idx = blockIdx.x * 256 + threadIdx.x;   // pair index over H*S/2
    const int hh = idx >> 11, p = idx & 2047;
    const int j = 2 * p;
    const float2 a  = E2p[hh * S + j];
    const float2 b  = E2p[hh * S + j + 1];
    const float  wa = 1.0f / Dcol[hh * S + j];
    const float  wb = 1.0f / Dcol[hh * S + j + 1];
    f16x2 qx, qy;
    qx[0] = (_Float16)(a.x * wa); qx[1] = (_Float16)(b.x * wb);
    qy[0] = (_Float16)(a.y * wa); qy[1] = (_Float16)(b.y * wb);
    wE2h[idx] = make_uint2(__builtin_bit_cast(unsigned int, qx),
                           __builtin_bit_cast(unsigned int, qy));
}

// ---------------------------------------------------------------------------
// k_attn: out[i, h*64+f] = elu( sum_j P[i,j]*hT[h][f][j] ), mfma 32x32x16 f16.
// 512 thr = 8 waves = 4 K-quarters x 2 M-waves; M=64, N=64, full K in-block
// (LDS cross-quarter reduce at end -> no atomics, ELU fused). Double-buffered
// B staging, one barrier/tile. A-frags in registers: v_pk_mul/v_pk_max +
// sign-smear bit masks. grid (S/64, H) = 512 blocks -> 2 blocks/CU, 16 w/CU.
// ---------------------------------------------------------------------------
__global__ __launch_bounds__(512, 4) void k_attn(const unsigned int* __restrict__ bm,
                                                 const float2* __restrict__ E1h,
                                                 const uint2* __restrict__ wE2h,
                                                 const unsigned short* __restrict__ hT,
                                                 float* __restrict__ out) {
    __shared__ __align__(16) char smem[65536];
    const int h  = blockIdx.y;
    const int i0 = blockIdx.x * 64;
    const int t  = threadIdx.x;
    const int lane = t & 63, wv = t >> 6;
    const int q = wv >> 1, mw = wv & 1;
    const int am = lane & 31, kh = lane >> 5;
    const int i  = i0 + mw * 32 + am;
    const int tq = t & 127;
    const int sf = tq >> 1;           // staging row f (0..63)
    const int sc = (tq & 1) * 4;      // staging chunk base (0 or 4)
    unsigned short* B0 = (unsigned short*)(smem + q * 16384);
    unsigned short* B1 = B0 + 4096;
    const int jbase = q * 1024;

    const float2 e1 = E1h[(size_t)i * H + h];
    f16x2 ea2, eb2;
    ea2[0] = ea2[1] = (_Float16)e1.x;
    eb2[0] = eb2[1] = (_Float16)e1.y;

    f32x16 acc0 = {0,0,0,0,0,0,0,0,0,0,0,0,0,0,0,0};
    f32x16 acc1 = {0,0,0,0,0,0,0,0,0,0,0,0,0,0,0,0};

    const unsigned short* hrow  = hT + ((h * FOUT + sf) * S) + jbase + sc * 8;
    const unsigned int*   bmrow = bm + (size_t)i * (S / 32) + (jbase >> 5);
    const uint2*          e2b   = wE2h + h * (S / 2) + (jbase >> 1) + kh * 4;

    // stage tile 0 into B0
    {
        const uint4* sp = (const uint4*)hrow;
        const uint4 v0 = sp[0], v1 = sp[1], v2 = sp[2], v3 = sp[3];
        *(uint4*)(B0 + sf * 64 + (((sc + 0) ^ (sf & 7)) * 8)) = v0;
        *(uint4*)(B0 + sf * 64 + (((sc + 1) ^ (sf & 7)) * 8)) = v1;
        *(uint4*)(B0 + sf * 64 + (((sc + 2) ^ (sf & 7)) * 8)) = v2;
        *(uint4*)(B0 + sf * 64 + (((sc + 3) ^ (sf & 7)) * 8)) = v3;
    }
    uint2 mrn = *(const uint2*)bmrow;
    __syncthreads();

    for (int jt = 0; jt < 16; ++jt) {
        unsigned short* Bc = (jt & 1) ? B1 : B0;
        unsigned short* Bn = (jt & 1) ? B0 : B1;
        const uint2 mr = mrn;
        if (jt < 15) {
            const uint4* sp = (const uint4*)(hrow + (jt + 1) * 64);
            const uint4 v0 = sp[0], v1 = sp[1], v2 = sp[2], v3 = sp[3];
            *(uint4*)(Bn + sf * 64 + (((sc + 0) ^ (sf & 7)) * 8)) = v0;
            *(uint4*)(Bn + sf * 64 + (((sc + 1) ^ (sf & 7)) * 8)) = v1;
            *(uint4*)(Bn + sf * 64 + (((sc + 2) ^ (sf & 7)) * 8)) = v2;
            *(uint4*)(Bn + sf * 64 + (((sc + 3) ^ (sf & 7)) * 8)) = v3;
            mrn = *(const uint2*)(bmrow + (jt + 1) * 2);
        }
        const unsigned int sh = kh * 8;
        unsigned int bys[4];
        bys[0] = (mr.x >> sh) & 0xffu;
        bys[1] = (mr.x >> (sh + 16)) & 0xffu;
        bys[2] = (mr.y >> sh) & 0xffu;
        bys[3] = (mr.y >> (sh + 16)) & 0xffu;
#pragma unroll
        for (int s = 0; s < 4; ++s) {
            const uint4 eA = *(const uint4*)(e2b + jt * 32 + s * 8);
            const uint4 eB = *(const uint4*)(e2b + jt * 32 + s * 8 + 2);
            const unsigned int by = bys[s];
            uint4 aw;
#define GAT_PAIR(pp, qxu, qyu, dst)                                               \
            {                                                                     \
                const f16x2 pa = ea2 * __builtin_bit_cast(f16x2, qxu);            \
                const f16x2 pb = eb2 * __builtin_bit_cast(f16x2, qyu);            \
                const unsigned int pm = __builtin_bit_cast(unsigned int,          \
                    __builtin_elementwise_max(pa, pb));                           \
                const unsigned int t2 = (by >> (2 * pp)) & 3u;                    \
                const unsigned int msk = ((0u - (t2 & 1u)) & 0xFFFFu) |           \
                                         ((0u - (t2 >> 1)) << 16);                \
                dst = pm & msk;                                                   \
            }
            GAT_PAIR(0, eA.x, eA.y, aw.x)
            GAT_PAIR(1, eA.z, eA.w, aw.y)
            GAT_PAIR(2, eB.x, eB.y, aw.z)
            GAT_PAIR(3, eB.z, eB.w, aw.w)
#undef GAT_PAIR
            const int chunk = s * 2 + kh;
            const f16x8 a  = __builtin_bit_cast(f16x8, aw);
            const f16x8 b0 = *(const f16x8*)(Bc + am * 64 + ((chunk ^ (am & 7)) * 8));
            const f16x8 b1 = *(const f16x8*)(Bc + (am + 32) * 64 + ((chunk ^ (am & 7)) * 8));
            acc0 = __builtin_amdgcn_mfma_f32_32x32x16_f16(a, b0, acc0, 0, 0, 0);
            acc1 = __builtin_amdgcn_mfma_f32_32x32x16_f16(a, b1, acc1, 0, 0, 0);
        }
        __syncthreads();
    }

    // ---- cross-quarter reduction in LDS (stride 36 floats: 16B-aligned, spread)
    float* r1 = (float*)smem;
    float* r3 = (float*)(smem + 18432);
    const int ro = (mw * 64 + lane) * 36;
    if (q == 1) {
#pragma unroll
        for (int r = 0; r < 16; ++r) { r1[ro + r] = acc0[r]; r1[ro + 16 + r] = acc1[r]; }
    }
    if (q == 3) {
#pragma unroll
        for (int r = 0; r < 16; ++r) { r3[ro + r] = acc0[r]; r3[ro + 16 + r] = acc1[r]; }
    }
    __syncthreads();
    if (q == 0) {
#pragma unroll
        for (int r = 0; r < 16; ++r) { acc0[r] += r1[ro + r]; acc1[r] += r1[ro + 16 + r]; }
    }
    if (q == 2) {
#pragma unroll
        for (int r = 0; r < 16; ++r) { acc0[r] += r3[ro + r]; acc1[r] += r3[ro + 16 + r]; }
    }
    __syncthreads();
    if (q == 2) {
#pragma unroll
        for (int r = 0; r < 16; ++r) { r1[ro + r] = acc0[r]; r1[ro + 16 + r] = acc1[r]; }
    }
    __syncthreads();
    if (q == 0) {
#pragma unroll
        for (int r = 0; r < 16; ++r) { acc0[r] += r1[ro + r]; acc1[r] += r1[ro + 16 + r]; }
        // C layout (32x32): col = lane&31, row = (r&3) + 8*(r>>2) + 4*(lane>>5)
#pragma unroll
        for (int r = 0; r < 16; ++r) {
            const int il  = (r & 3) + 8 * (r >> 2) + 4 * kh;
            const int row = i0 + mw * 32 + il;
            const float x0 = acc0[r], x1 = acc1[r];
            out[row * (H * FOUT) + h * FOUT + am]      = x0 > 0.f ? x0 : __expf(x0) - 1.f;
            out[row * (H * FOUT) + h * FOUT + 32 + am] = x1 > 0.f ? x1 : __expf(x1) - 1.f;
        }
    }
}

extern "C" void kernel_launch(void* const* d_in, const int* in_sizes, int n_in,
                              void* d_out, int out_size, void* d_ws, size_t ws_size,
                              hipStream_t stream) {
    const float* X   = (const float*)d_in[0];  // [1,4096,128]
    const int*   adj = (const int*)d_in[1];    // [1,4096,4096]
    const float* W   = (const float*)d_in[2];  // [8,128,64]
    const float* a1  = (const float*)d_in[3];  // [8,64,1]
    const float* a2  = (const float*)d_in[4];  // [8,64,1]
    float* out = (float*)d_out;                // [4096, 512]

    char* ws = (char*)d_ws;
    unsigned short* hT   = (unsigned short*)ws;               // 4 MB fp16
    float2*         E1h  = (float2*)(ws + 4194304);           // 256 KB [i][h]
    float2*         E2p  = (float2*)(ws + 4456448);           // 256 KB [h][j]
    float*          Dcol = (float*)(ws + 4718592);            // 128 KB
    uint2*          wE2h = (uint2*)(ws + 4849664);            // 128 KB
    unsigned int*   bm   = (unsigned int*)(ws + 4980736);     // 2 MB
    // total ~6.75 MB

    (void)hipMemsetAsync(Dcol, 0, H * S * sizeof(float), stream);
    k_proj  <<<dim3(S / 64, H),       256, 0, stream>>>(X, W, a1, a2, hT, E1h, E2p);
    k_colsum<<<dim3(S / 64, S / 256), 256, 0, stream>>>(adj, E1h, E2p, Dcol, bm);
    k_finish<<<dim3(H * S / 512),     256, 0, stream>>>(Dcol, E2p, wE2h);
    k_attn  <<<dim3(S / 64, H),       512, 0, stream>>>(bm, E1h, wE2h, hT, out);
}

// Round 7
// 211.188 us; speedup vs baseline: 2.1120x; 1.0013x over previous
//
#include <hip/hip_runtime.h>

#define S 4096
#define PS 4128            // padded hT row stride in elems (breaks 8KB L1 aliasing)
#define FIN 128
#define FOUT 64
#define H 8
#define ALPHA 0.2f

typedef __attribute__((ext_vector_type(2)))  _Float16 f16x2;
typedef __attribute__((ext_vector_type(8)))  _Float16 f16x8;
typedef __attribute__((ext_vector_type(16))) float    f32x16;

__device__ __forceinline__ unsigned short f2h(float x) {
    return __builtin_bit_cast(unsigned short, (_Float16)x);  // RTNE
}

// ---------------------------------------------------------------------------
// k_proj: h = X·W (fp32), hT[h][f][j] fp16 with padded row stride PS;
// f1=h·a1, f2=h·a2 -> E1h[i][h]=(e^f1,e^{a f1}); E2p[h][j]=(e^f2,e^{a f2}).
// ---------------------------------------------------------------------------
__global__ __launch_bounds__(256) void k_proj(const float* __restrict__ X,
                                              const float* __restrict__ W,
                                              const float* __restrict__ a1,
                                              const float* __restrict__ a2,
                                              unsigned short* __restrict__ hT,
                                              float2* __restrict__ E1h,
                                              float2* __restrict__ E2p) {
    __shared__ float xs[64][36];
    __shared__ float Ws[32][68];
    const int h  = blockIdx.y;
    const int j0 = blockIdx.x * 64;
    const int t  = threadIdx.x;
    const int fg = t & 15, rg = t >> 4;
    const int jr = t >> 2, q = t & 3;
    const int kw = t >> 3, cw = t & 7;
    float acc[4][4] = {};
#pragma unroll
    for (int k0 = 0; k0 < FIN; k0 += 32) {
        *(float4*)&xs[jr][q * 8]      = *(const float4*)&X[(j0 + jr) * FIN + k0 + q * 8];
        *(float4*)&xs[jr][q * 8 + 4]  = *(const float4*)&X[(j0 + jr) * FIN + k0 + q * 8 + 4];
        *(float4*)&Ws[kw][cw * 8]     = *(const float4*)&W[(h * FIN + k0 + kw) * FOUT + cw * 8];
        *(float4*)&Ws[kw][cw * 8 + 4] = *(const float4*)&W[(h * FIN + k0 + kw) * FOUT + cw * 8 + 4];
        __syncthreads();
#pragma unroll
        for (int kc = 0; kc < 8; ++kc) {
            float4 xr[4], wr[4];
#pragma unroll
            for (int r = 0; r < 4; ++r) xr[r] = *(const float4*)&xs[4 * rg + r][kc * 4];
#pragma unroll
            for (int kk = 0; kk < 4; ++kk) wr[kk] = *(const float4*)&Ws[kc * 4 + kk][fg * 4];
#pragma unroll
            for (int r = 0; r < 4; ++r) {
                const float* xp = (const float*)&xr[r];
#pragma unroll
                for (int kk = 0; kk < 4; ++kk) {
                    const float xv = xp[kk];
                    acc[r][0] += xv * wr[kk].x;
                    acc[r][1] += xv * wr[kk].y;
                    acc[r][2] += xv * wr[kk].z;
                    acc[r][3] += xv * wr[kk].w;
                }
            }
        }
        __syncthreads();
    }
    const float4 a1v = *(const float4*)&a1[h * FOUT + fg * 4];
    const float4 a2v = *(const float4*)&a2[h * FOUT + fg * 4];
#pragma unroll
    for (int r = 0; r < 4; ++r) {
        float p1 = acc[r][0] * a1v.x + acc[r][1] * a1v.y + acc[r][2] * a1v.z + acc[r][3] * a1v.w;
        float p2 = acc[r][0] * a2v.x + acc[r][1] * a2v.y + acc[r][2] * a2v.z + acc[r][3] * a2v.w;
#pragma unroll
        for (int off = 1; off < 16; off <<= 1) {
            p1 += __shfl_xor(p1, off, 64);
            p2 += __shfl_xor(p2, off, 64);
        }
        if (fg == 0) {
            const int row = j0 + 4 * rg + r;
            E1h[(size_t)row * H + h] = make_float2(__expf(p1), __expf(ALPHA * p1));
            E2p[h * S + row]         = make_float2(__expf(p2), __expf(ALPHA * p2));
        }
    }
#pragma unroll
    for (int c = 0; c < 4; ++c) {
        ushort4 pk;
        pk.x = f2h(acc[0][c]);
        pk.y = f2h(acc[1][c]);
        pk.z = f2h(acc[2][c]);
        pk.w = f2h(acc[3][c]);
        *(ushort4*)&hT[(size_t)(h * FOUT + fg * 4 + c) * PS + j0 + 4 * rg] = pk;
    }
}

// ---------------------------------------------------------------------------
// k_colsum: Dpart[z,h,j] = sum_{i in chunk z} adj(i,j)*max(E1x*E2x, E1y*E2y);
// packs adj into TRANSPOSED bitmask bmT[jword][i] (coalesced reads in k_attn).
// grid (S/64 j-tiles, S/256 i-chunks), 256 thr.
// ---------------------------------------------------------------------------
__global__ __launch_bounds__(256) void k_colsum(const int* __restrict__ adj,
                                                const float2* __restrict__ E1h,
                                                const float2* __restrict__ E2p,
                                                float* __restrict__ Dpart,
                                                unsigned int* __restrict__ bmT) {
    __shared__ float red[4][H][64];
    const int j0    = blockIdx.x * 64;
    const int ibase = blockIdx.y * 256;
    const int t  = threadIdx.x;
    const int jl = t & 63;
    const int wv = __builtin_amdgcn_readfirstlane(t >> 6);
    float2 e2v[H];
    float Dl[H];
#pragma unroll
    for (int hh = 0; hh < H; ++hh) { e2v[hh] = E2p[hh * S + j0 + jl]; Dl[hh] = 0.f; }
    const int rowbase = ibase + wv * 64;
    for (int s = 0; s < 64; ++s) {
        const int row = rowbase + s;
        const float2* __restrict__ e1r = E1h + (size_t)row * H;  // wave-uniform
        const int av = adj[(size_t)row * S + j0 + jl];
        const unsigned long long blt = __ballot(av != 0);
        if (jl == 0) {
            bmT[(j0 >> 5) * S + row]       = (unsigned int)blt;
            bmT[((j0 >> 5) + 1) * S + row] = (unsigned int)(blt >> 32);
        }
        const float bf = av != 0 ? 1.f : 0.f;
#pragma unroll
        for (int hh = 0; hh < H; ++hh) {
            const float2 e1 = e1r[hh];
            Dl[hh] = fmaf(bf, fmaxf(e1.x * e2v[hh].x, e1.y * e2v[hh].y), Dl[hh]);
        }
    }
#pragma unroll
    for (int hh = 0; hh < H; ++hh) red[wv][hh][jl] = Dl[hh];
    __syncthreads();
    if (wv == 0) {
#pragma unroll
        for (int hh = 0; hh < H; ++hh) {
            const float sum = red[0][hh][jl] + red[1][hh][jl] +
                              red[2][hh][jl] + red[3][hh][jl];
            Dpart[(blockIdx.y * H + hh) * S + j0 + jl] = sum;
        }
    }
}

// ---------------------------------------------------------------------------
// k_attn: out[i, h*64+f] = elu( sum_j P[i,j]*hT[h][f][j] ), mfma 32x32x16 f16.
// Prologue: block computes its head's wE2 = fp16(E2pair/colsum) into LDS.
// K-loop: ZERO barriers — A-frags built in registers (E1 regs × wE2 LDS
// broadcasts × bmT coalesced bits); B-frags loaded DIRECTLY from global hT
// (L2-resident, PS-padded vs L1 set aliasing). 512 thr = 4 K-quarters × 2
// M-waves; LDS cross-quarter reduce; fused ELU store. grid (S/64, H).
// ---------------------------------------------------------------------------
__global__ __launch_bounds__(512, 4) void k_attn(const unsigned int* __restrict__ bmT,
                                                 const float2* __restrict__ E1h,
                                                 const float* __restrict__ Dpart,
                                                 const float2* __restrict__ E2p,
                                                 const unsigned short* __restrict__ hT,
                                                 float* __restrict__ out) {
    __shared__ __align__(16) char smem[53248];  // wE2s 16K | r1 18K | r3 18K
    const int h  = blockIdx.y;
    const int i0 = blockIdx.x * 64;
    const int t  = threadIdx.x;

    // ---- prologue: wE2s[pair] for all 2048 j-pairs of this head ----
    uint2* wE2s = (uint2*)smem;
#pragma unroll
    for (int u = 0; u < 4; ++u) {
        const int pair = t * 4 + u;
        const int j = 2 * pair;
        float sx = 0.f, sy = 0.f;
#pragma unroll
        for (int z = 0; z < 16; ++z) {
            const float2 d = *(const float2*)&Dpart[(z * H + h) * S + j];
            sx += d.x; sy += d.y;
        }
        const float4 e2 = *(const float4*)&E2p[h * S + j];  // (x0,y0,x1,y1)
        const float wa = 1.0f / sx, wb = 1.0f / sy;
        f16x2 qx, qy;
        qx[0] = (_Float16)(e2.x * wa); qx[1] = (_Float16)(e2.z * wb);
        qy[0] = (_Float16)(e2.y * wa); qy[1] = (_Float16)(e2.w * wb);
        wE2s[pair] = make_uint2(__builtin_bit_cast(unsigned int, qx),
                                __builtin_bit_cast(unsigned int, qy));
    }
    __syncthreads();

    // ---- main loop ----
    const int lane = t & 63, wv = t >> 6;
    const int q = wv >> 1, mw = wv & 1;
    const int am = lane & 31, kh = lane >> 5;
    const int i  = i0 + mw * 32 + am;
    const int jbase = q * 1024;

    const float2 e1 = E1h[(size_t)i * H + h];
    f16x2 ea2, eb2;
    ea2[0] = ea2[1] = (_Float16)e1.x;
    eb2[0] = eb2[1] = (_Float16)e1.y;

    f32x16 acc0 = {0,0,0,0,0,0,0,0,0,0,0,0,0,0,0,0};
    f32x16 acc1 = {0,0,0,0,0,0,0,0,0,0,0,0,0,0,0,0};

    const unsigned short* b0p = hT + (size_t)(h * FOUT + am) * PS + jbase;
    const unsigned short* b1p = hT + (size_t)(h * FOUT + am + 32) * PS + jbase;
    const unsigned int* bmcol = bmT + (jbase >> 5) * S + i;
    const uint2* e2s = wE2s + (jbase >> 1) + kh * 4;
    const unsigned int sh = kh * 8;

    for (int jt = 0; jt < 16; ++jt) {
        const unsigned int w0 = bmcol[(2 * jt) * S];
        const unsigned int w1 = bmcol[(2 * jt + 1) * S];
        unsigned int bys[4];
        bys[0] = (w0 >> sh) & 0xffu;
        bys[1] = (w0 >> (sh + 16)) & 0xffu;
        bys[2] = (w1 >> sh) & 0xffu;
        bys[3] = (w1 >> (sh + 16)) & 0xffu;
#pragma unroll
        for (int s = 0; s < 4; ++s) {
            const int ko = jt * 64 + s * 16 + kh * 8;
            const f16x8 b0 = *(const f16x8*)(b0p + ko);
            const f16x8 b1 = *(const f16x8*)(b1p + ko);
            const uint4 eA = *(const uint4*)(e2s + jt * 32 + s * 8);
            const uint4 eB = *(const uint4*)(e2s + jt * 32 + s * 8 + 2);
            const unsigned int by = bys[s];
            uint4 aw;
#define GAT_PAIR(pp, qxu, qyu, dst)                                               \
            {                                                                     \
                const f16x2 pa = ea2 * __builtin_bit_cast(f16x2, qxu);            \
                const f16x2 pb = eb2 * __builtin_bit_cast(f16x2, qyu);            \
                const unsigned int pm = __builtin_bit_cast(unsigned int,          \
                    __builtin_elementwise_max(pa, pb));                           \
                const unsigned int t2 = (by >> (2 * pp)) & 3u;                    \
                const unsigned int msk = ((0u - (t2 & 1u)) & 0xFFFFu) |           \
                                         ((0u - (t2 >> 1)) << 16);                \
                dst = pm & msk;                                                   \
            }
            GAT_PAIR(0, eA.x, eA.y, aw.x)
            GAT_PAIR(1, eA.z, eA.w, aw.y)
            GAT_PAIR(2, eB.x, eB.y, aw.z)
            GAT_PAIR(3, eB.z, eB.w, aw.w)
#undef GAT_PAIR
            const f16x8 a = __builtin_bit_cast(f16x8, aw);
            acc0 = __builtin_amdgcn_mfma_f32_32x32x16_f16(a, b0, acc0, 0, 0, 0);
            acc1 = __builtin_amdgcn_mfma_f32_32x32x16_f16(a, b1, acc1, 0, 0, 0);
        }
    }
    __syncthreads();

    // ---- cross-quarter reduction in LDS (stride 36 floats) ----
    float* r1 = (float*)(smem + 16384);
    float* r3 = (float*)(smem + 16384 + 18432);
    const int ro = (mw * 64 + lane) * 36;
    if (q == 1) {
#pragma unroll
        for (int r = 0; r < 16; ++r) { r1[ro + r] = acc0[r]; r1[ro + 16 + r] = acc1[r]; }
    }
    if (q == 3) {
#pragma unroll
        for (int r = 0; r < 16; ++r) { r3[ro + r] = acc0[r]; r3[ro + 16 + r] = acc1[r]; }
    }
    __syncthreads();
    if (q == 0) {
#pragma unroll
        for (int r = 0; r < 16; ++r) { acc0[r] += r1[ro + r]; acc1[r] += r1[ro + 16 + r]; }
    }
    if (q == 2) {
#pragma unroll
        for (int r = 0; r < 16; ++r) { acc0[r] += r3[ro + r]; acc1[r] += r3[ro + 16 + r]; }
    }
    __syncthreads();
    if (q == 2) {
#pragma unroll
        for (int r = 0; r < 16; ++r) { r1[ro + r] = acc0[r]; r1[ro + 16 + r] = acc1[r]; }
    }
    __syncthreads();
    if (q == 0) {
#pragma unroll
        for (int r = 0; r < 16; ++r) { acc0[r] += r1[ro + r]; acc1[r] += r1[ro + 16 + r]; }
        // C layout (32x32): col = lane&31, row = (r&3) + 8*(r>>2) + 4*(lane>>5)
#pragma unroll
        for (int r = 0; r < 16; ++r) {
            const int il  = (r & 3) + 8 * (r >> 2) + 4 * kh;
            const int row = i0 + mw * 32 + il;
            const float x0 = acc0[r], x1 = acc1[r];
            out[row * (H * FOUT) + h * FOUT + am]      = x0 > 0.f ? x0 : __expf(x0) - 1.f;
            out[row * (H * FOUT) + h * FOUT + 32 + am] = x1 > 0.f ? x1 : __expf(x1) - 1.f;
        }
    }
}

extern "C" void kernel_launch(void* const* d_in, const int* in_sizes, int n_in,
                              void* d_out, int out_size, void* d_ws, size_t ws_size,
                              hipStream_t stream) {
    const float* X   = (const float*)d_in[0];  // [1,4096,128]
    const int*   adj = (const int*)d_in[1];    // [1,4096,4096]
    const float* W   = (const float*)d_in[2];  // [8,128,64]
    const float* a1  = (const float*)d_in[3];  // [8,64,1]
    const float* a2  = (const float*)d_in[4];  // [8,64,1]
    float* out = (float*)d_out;                // [4096, 512]

    char* ws = (char*)d_ws;
    unsigned short* hT   = (unsigned short*)ws;               // H*FOUT*PS fp16 ≈ 4.03 MB
    float2*         E1h  = (float2*)(ws + 4325376);           // 256 KB [i][h]
    float2*         E2p  = (float2*)(ws + 4587520);           // 256 KB [h][j]
    float*          Dpart= (float*)(ws + 4849664);            // 2 MB [z16][h][j]
    unsigned int*   bmT  = (unsigned int*)(ws + 6946816);     // 2 MB [jword][i]
    // total ~8.6 MB

    k_proj  <<<dim3(S / 64, H),       256, 0, stream>>>(X, W, a1, a2, hT, E1h, E2p);
    k_colsum<<<dim3(S / 64, S / 256), 256, 0, stream>>>(adj, E1h, E2p, Dpart, bmT);
    k_attn  <<<dim3(S / 64, H),       512, 0, stream>>>(bmT, E1h, Dpart, E2p, hT, out);
}

// Round 8
// 209.571 us; speedup vs baseline: 2.1283x; 1.0077x over previous
//
#include <hip/hip_runtime.h>

#define S 4096
#define PS 4128            // padded hT row stride in elems (breaks 8KB L1 aliasing)
#define FIN 128
#define FOUT 64
#define H 8
#define ALPHA 0.2f

typedef __attribute__((ext_vector_type(2)))  _Float16 f16x2;
typedef __attribute__((ext_vector_type(8)))  _Float16 f16x8;
typedef __attribute__((ext_vector_type(16))) float    f32x16;

__device__ __forceinline__ unsigned short f2h(float x) {
    return __builtin_bit_cast(unsigned short, (_Float16)x);  // RTNE
}

// ---------------------------------------------------------------------------
// k_proj: h = X·W (fp32), hT[h][f][j] fp16 with padded row stride PS;
// f1=h·a1, f2=h·a2 -> E1h[i][h]=(e^f1,e^{a f1}); E2p[h][j]=(e^f2,e^{a f2}).
// ---------------------------------------------------------------------------
__global__ __launch_bounds__(256) void k_proj(const float* __restrict__ X,
                                              const float* __restrict__ W,
                                              const float* __restrict__ a1,
                                              const float* __restrict__ a2,
                                              unsigned short* __restrict__ hT,
                                              float2* __restrict__ E1h,
                                              float2* __restrict__ E2p) {
    __shared__ float xs[64][36];
    __shared__ float Ws[32][68];
    const int h  = blockIdx.y;
    const int j0 = blockIdx.x * 64;
    const int t  = threadIdx.x;
    const int fg = t & 15, rg = t >> 4;
    const int jr = t >> 2, q = t & 3;
    const int kw = t >> 3, cw = t & 7;
    float acc[4][4] = {};
#pragma unroll
    for (int k0 = 0; k0 < FIN; k0 += 32) {
        *(float4*)&xs[jr][q * 8]      = *(const float4*)&X[(j0 + jr) * FIN + k0 + q * 8];
        *(float4*)&xs[jr][q * 8 + 4]  = *(const float4*)&X[(j0 + jr) * FIN + k0 + q * 8 + 4];
        *(float4*)&Ws[kw][cw * 8]     = *(const float4*)&W[(h * FIN + k0 + kw) * FOUT + cw * 8];
        *(float4*)&Ws[kw][cw * 8 + 4] = *(const float4*)&W[(h * FIN + k0 + kw) * FOUT + cw * 8 + 4];
        __syncthreads();
#pragma unroll
        for (int kc = 0; kc < 8; ++kc) {
            float4 xr[4], wr[4];
#pragma unroll
            for (int r = 0; r < 4; ++r) xr[r] = *(const float4*)&xs[4 * rg + r][kc * 4];
#pragma unroll
            for (int kk = 0; kk < 4; ++kk) wr[kk] = *(const float4*)&Ws[kc * 4 + kk][fg * 4];
#pragma unroll
            for (int r = 0; r < 4; ++r) {
                const float* xp = (const float*)&xr[r];
#pragma unroll
                for (int kk = 0; kk < 4; ++kk) {
                    const float xv = xp[kk];
                    acc[r][0] += xv * wr[kk].x;
                    acc[r][1] += xv * wr[kk].y;
                    acc[r][2] += xv * wr[kk].z;
                    acc[r][3] += xv * wr[kk].w;
                }
            }
        }
        __syncthreads();
    }
    const float4 a1v = *(const float4*)&a1[h * FOUT + fg * 4];
    const float4 a2v = *(const float4*)&a2[h * FOUT + fg * 4];
#pragma unroll
    for (int r = 0; r < 4; ++r) {
        float p1 = acc[r][0] * a1v.x + acc[r][1] * a1v.y + acc[r][2] * a1v.z + acc[r][3] * a1v.w;
        float p2 = acc[r][0] * a2v.x + acc[r][1] * a2v.y + acc[r][2] * a2v.z + acc[r][3] * a2v.w;
#pragma unroll
        for (int off = 1; off < 16; off <<= 1) {
            p1 += __shfl_xor(p1, off, 64);
            p2 += __shfl_xor(p2, off, 64);
        }
        if (fg == 0) {
            const int row = j0 + 4 * rg + r;
            E1h[(size_t)row * H + h] = make_float2(__expf(p1), __expf(ALPHA * p1));
            E2p[h * S + row]         = make_float2(__expf(p2), __expf(ALPHA * p2));
        }
    }
#pragma unroll
    for (int c = 0; c < 4; ++c) {
        ushort4 pk;
        pk.x = f2h(acc[0][c]);
        pk.y = f2h(acc[1][c]);
        pk.z = f2h(acc[2][c]);
        pk.w = f2h(acc[3][c]);
        *(ushort4*)&hT[(size_t)(h * FOUT + fg * 4 + c) * PS + j0 + 4 * rg] = pk;
    }
}

// ---------------------------------------------------------------------------
// k_colsum: Dpart[z,h,j] = sum_{i in chunk z} adj(i,j)*max(E1x*E2x, E1y*E2y);
// packs adj into TRANSPOSED bitmask bmT[jword][i].
// grid (S/64 j-tiles, S/256 i-chunks), 256 thr.
// ---------------------------------------------------------------------------
__global__ __launch_bounds__(256) void k_colsum(const int* __restrict__ adj,
                                                const float2* __restrict__ E1h,
                                                const float2* __restrict__ E2p,
                                                float* __restrict__ Dpart,
                                                unsigned int* __restrict__ bmT) {
    __shared__ float red[4][H][64];
    const int j0    = blockIdx.x * 64;
    const int ibase = blockIdx.y * 256;
    const int t  = threadIdx.x;
    const int jl = t & 63;
    const int wv = __builtin_amdgcn_readfirstlane(t >> 6);
    float2 e2v[H];
    float Dl[H];
#pragma unroll
    for (int hh = 0; hh < H; ++hh) { e2v[hh] = E2p[hh * S + j0 + jl]; Dl[hh] = 0.f; }
    const int rowbase = ibase + wv * 64;
    for (int s = 0; s < 64; ++s) {
        const int row = rowbase + s;
        const float2* __restrict__ e1r = E1h + (size_t)row * H;  // wave-uniform
        const int av = adj[(size_t)row * S + j0 + jl];
        const unsigned long long blt = __ballot(av != 0);
        if (jl == 0) {
            bmT[(j0 >> 5) * S + row]       = (unsigned int)blt;
            bmT[((j0 >> 5) + 1) * S + row] = (unsigned int)(blt >> 32);
        }
        const float bf = av != 0 ? 1.f : 0.f;
#pragma unroll
        for (int hh = 0; hh < H; ++hh) {
            const float2 e1 = e1r[hh];
            Dl[hh] = fmaf(bf, fmaxf(e1.x * e2v[hh].x, e1.y * e2v[hh].y), Dl[hh]);
        }
    }
#pragma unroll
    for (int hh = 0; hh < H; ++hh) red[wv][hh][jl] = Dl[hh];
    __syncthreads();
    if (wv == 0) {
#pragma unroll
        for (int hh = 0; hh < H; ++hh) {
            const float sum = red[0][hh][jl] + red[1][hh][jl] +
                              red[2][hh][jl] + red[3][hh][jl];
            Dpart[(blockIdx.y * H + hh) * S + j0 + jl] = sum;
        }
    }
}

// ---------------------------------------------------------------------------
// k_finish: wE2h[h][pair] = { h2(qx_j,qx_j1), h2(qy_j,qy_j1) },
// q = E2pair / colsum  (w folded in, packed fp16 SoA pairs for k_attn)
// ---------------------------------------------------------------------------
__global__ __launch_bounds__(256) void k_finish(const float* __restrict__ Dpart,
                                                const float2* __restrict__ E2p,
                                                uint2* __restrict__ wE2h) {
    const int idx = blockIdx.x * 256 + threadIdx.x;   // pair index over H*S/2
    const int hh = idx >> 11, pp = idx & 2047;
    const int j = 2 * pp;
    float sx = 0.f, sy = 0.f;
#pragma unroll
    for (int z = 0; z < 16; ++z) {
        const float2 d = *(const float2*)&Dpart[(z * H + hh) * S + j];
        sx += d.x; sy += d.y;
    }
    const float4 e2 = *(const float4*)&E2p[hh * S + j];  // (x0,y0,x1,y1)
    const float wa = 1.0f / sx, wb = 1.0f / sy;
    f16x2 qx, qy;
    qx[0] = (_Float16)(e2.x * wa); qx[1] = (_Float16)(e2.z * wb);
    qy[0] = (_Float16)(e2.y * wa); qy[1] = (_Float16)(e2.w * wb);
    wE2h[idx] = make_uint2(__builtin_bit_cast(unsigned int, qx),
                           __builtin_bit_cast(unsigned int, qy));
}

// ---------------------------------------------------------------------------
// k_attn: partial[z][i, h*64+f] = sum_{j in half z} P[i,j]*hT[h][f][j],
// mfma 32x32x16 f16. grid (S/64, H, 2 K-halves) = 1024 blocks; 512 thr =
// 2 M-waves x 4 K-slices (512 j each). A-frags in registers; B-frags direct
// from global hT (L1/L2-hot, PS-padded). LDS: 8KB wE2 slice (prologue copy),
// reused for the cross-slice reduction -> 36.9 KB total -> 3 blocks/CU =
// 24 waves/CU (the point of this round). No atomics; k_elu combines halves.
// ---------------------------------------------------------------------------
__global__ __launch_bounds__(512, 6) void k_attn(const unsigned int* __restrict__ bmT,
                                                 const float2* __restrict__ E1h,
                                                 const uint2* __restrict__ wE2h,
                                                 const unsigned short* __restrict__ hT,
                                                 float* __restrict__ outp) {
    __shared__ __align__(16) char smem[36864];
    const int h  = blockIdx.y;
    const int i0 = blockIdx.x * 64;
    const int z  = blockIdx.z;
    const int t  = threadIdx.x;

    // ---- prologue: copy this half's 1024 wE2 pairs (8 KB) into LDS ----
    uint2* wE2s = (uint2*)smem;
    ((uint4*)wE2s)[t] = ((const uint4*)(wE2h + h * (S / 2) + z * 1024))[t];
    __syncthreads();

    const int lane = t & 63, wv = t >> 6;
    const int q = wv >> 1, mw = wv & 1;
    const int am = lane & 31, kh = lane >> 5;
    const int i  = i0 + mw * 32 + am;
    const int jbase = z * 2048 + q * 512;   // global j start for this wave

    const float2 e1 = E1h[(size_t)i * H + h];
    f16x2 ea2, eb2;
    ea2[0] = ea2[1] = (_Float16)e1.x;
    eb2[0] = eb2[1] = (_Float16)e1.y;

    f32x16 acc0 = {0,0,0,0,0,0,0,0,0,0,0,0,0,0,0,0};
    f32x16 acc1 = {0,0,0,0,0,0,0,0,0,0,0,0,0,0,0,0};

    const unsigned short* b0p = hT + (size_t)(h * FOUT + am) * PS + jbase;
    const unsigned short* b1p = hT + (size_t)(h * FOUT + am + 32) * PS + jbase;
    const unsigned int* bmcol = bmT + (jbase >> 5) * S + i;
    const uint2* e2s = wE2s + q * 256 + kh * 4;
    const unsigned int sh = kh * 8;

    for (int jt = 0; jt < 8; ++jt) {
        const unsigned int w0 = bmcol[(2 * jt) * S];
        const unsigned int w1 = bmcol[(2 * jt + 1) * S];
        unsigned int bys[4];
        bys[0] = (w0 >> sh) & 0xffu;
        bys[1] = (w0 >> (sh + 16)) & 0xffu;
        bys[2] = (w1 >> sh) & 0xffu;
        bys[3] = (w1 >> (sh + 16)) & 0xffu;
#pragma unroll
        for (int s = 0; s < 4; ++s) {
            const int ko = jt * 64 + s * 16 + kh * 8;
            const f16x8 b0 = *(const f16x8*)(b0p + ko);
            const f16x8 b1 = *(const f16x8*)(b1p + ko);
            const uint4 eA = *(const uint4*)(e2s + jt * 32 + s * 8);
            const uint4 eB = *(const uint4*)(e2s + jt * 32 + s * 8 + 2);
            const unsigned int by = bys[s];
            uint4 aw;
#define GAT_PAIR(pp, qxu, qyu, dst)                                               \
            {                                                                     \
                const f16x2 pa = ea2 * __builtin_bit_cast(f16x2, qxu);            \
                const f16x2 pb = eb2 * __builtin_bit_cast(f16x2, qyu);            \
                const unsigned int pm = __builtin_bit_cast(unsigned int,          \
                    __builtin_elementwise_max(pa, pb));                           \
                const unsigned int t2 = (by >> (2 * pp)) & 3u;                    \
                const unsigned int msk = ((0u - (t2 & 1u)) & 0xFFFFu) |           \
                                         ((0u - (t2 >> 1)) << 16);                \
                dst = pm & msk;                                                   \
            }
            GAT_PAIR(0, eA.x, eA.y, aw.x)
            GAT_PAIR(1, eA.z, eA.w, aw.y)
            GAT_PAIR(2, eB.x, eB.y, aw.z)
            GAT_PAIR(3, eB.z, eB.w, aw.w)
#undef GAT_PAIR
            const f16x8 a = __builtin_bit_cast(f16x8, aw);
            acc0 = __builtin_amdgcn_mfma_f32_32x32x16_f16(a, b0, acc0, 0, 0, 0);
            acc1 = __builtin_amdgcn_mfma_f32_32x32x16_f16(a, b1, acc1, 0, 0, 0);
        }
    }
    __syncthreads();   // wE2s dead from here; reuse smem for reduction

    // ---- cross-slice reduction in LDS (stride 36 floats) ----
    float* r1 = (float*)smem;
    float* r3 = (float*)(smem + 18432);
    const int ro = (mw * 64 + lane) * 36;
    if (q == 1) {
#pragma unroll
        for (int r = 0; r < 16; ++r) { r1[ro + r] = acc0[r]; r1[ro + 16 + r] = acc1[r]; }
    }
    if (q == 3) {
#pragma unroll
        for (int r = 0; r < 16; ++r) { r3[ro + r] = acc0[r]; r3[ro + 16 + r] = acc1[r]; }
    }
    __syncthreads();
    if (q == 0) {
#pragma unroll
        for (int r = 0; r < 16; ++r) { acc0[r] += r1[ro + r]; acc1[r] += r1[ro + 16 + r]; }
    }
    if (q == 2) {
#pragma unroll
        for (int r = 0; r < 16; ++r) { acc0[r] += r3[ro + r]; acc1[r] += r3[ro + 16 + r]; }
    }
    __syncthreads();
    if (q == 2) {
#pragma unroll
        for (int r = 0; r < 16; ++r) { r1[ro + r] = acc0[r]; r1[ro + 16 + r] = acc1[r]; }
    }
    __syncthreads();
    if (q == 0) {
#pragma unroll
        for (int r = 0; r < 16; ++r) { acc0[r] += r1[ro + r]; acc1[r] += r1[ro + 16 + r]; }
        float* dst = outp + (size_t)z * (S * H * FOUT);
        // C layout (32x32): col = lane&31, row = (r&3) + 8*(r>>2) + 4*(lane>>5)
#pragma unroll
        for (int r = 0; r < 16; ++r) {
            const int il  = (r & 3) + 8 * (r >> 2) + 4 * kh;
            const int row = i0 + mw * 32 + il;
            dst[row * (H * FOUT) + h * FOUT + am]      = acc0[r];
            dst[row * (H * FOUT) + h * FOUT + 32 + am] = acc1[r];
        }
    }
}

// ---------------------------------------------------------------------------
// k_elu: out = elu(partial0 + partial1)
// ---------------------------------------------------------------------------
__global__ __launch_bounds__(256) void k_elu(const float* __restrict__ outp,
                                             float* __restrict__ out) {
    const int idx = (blockIdx.x * 256 + threadIdx.x) * 4;
    const float4 p0 = *(const float4*)&outp[idx];
    const float4 p1 = *(const float4*)&outp[S * H * FOUT + idx];
    float4 v;
    v.x = p0.x + p1.x; v.y = p0.y + p1.y; v.z = p0.z + p1.z; v.w = p0.w + p1.w;
    v.x = v.x > 0.f ? v.x : __expf(v.x) - 1.f;
    v.y = v.y > 0.f ? v.y : __expf(v.y) - 1.f;
    v.z = v.z > 0.f ? v.z : __expf(v.z) - 1.f;
    v.w = v.w > 0.f ? v.w : __expf(v.w) - 1.f;
    *(float4*)&out[idx] = v;
}

extern "C" void kernel_launch(void* const* d_in, const int* in_sizes, int n_in,
                              void* d_out, int out_size, void* d_ws, size_t ws_size,
                              hipStream_t stream) {
    const float* X   = (const float*)d_in[0];  // [1,4096,128]
    const int*   adj = (const int*)d_in[1];    // [1,4096,4096]
    const float* W   = (const float*)d_in[2];  // [8,128,64]
    const float* a1  = (const float*)d_in[3];  // [8,64,1]
    const float* a2  = (const float*)d_in[4];  // [8,64,1]
    float* out = (float*)d_out;                // [4096, 512]

    char* ws = (char*)d_ws;
    unsigned short* hT   = (unsigned short*)ws;               // ≈4.03 MB fp16, PS stride
    float2*         E1h  = (float2*)(ws + 4325376);           // 256 KB [i][h]
    float2*         E2p  = (float2*)(ws + 4587520);           // 256 KB [h][j]
    float*          Dpart= (float*)(ws + 4849664);            // 2 MB [z16][h][j]
    unsigned int*   bmT  = (unsigned int*)(ws + 6946816);     // 2 MB [jword][i]
    uint2*          wE2h = (uint2*)(ws + 9043968);            // 128 KB [h][pair]
    float*          outp = (float*)(ws + 9175040);            // 16 MB [z2][i][hf]
    // total ~25.7 MB

    k_proj  <<<dim3(S / 64, H),       256, 0, stream>>>(X, W, a1, a2, hT, E1h, E2p);
    k_colsum<<<dim3(S / 64, S / 256), 256, 0, stream>>>(adj, E1h, E2p, Dpart, bmT);
    k_finish<<<dim3(H * S / 512),     256, 0, stream>>>(Dpart, E2p, wE2h);
    k_attn  <<<dim3(S / 64, H, 2),    512, 0, stream>>>(bmT, E1h, wE2h, hT, outp);
    k_elu   <<<dim3(S * H * FOUT / 1024), 256, 0, stream>>>(outp, out);
}

// Round 10
// 191.450 us; speedup vs baseline: 2.3297x; 1.0947x over previous
//
#include <hip/hip_runtime.h>

#define S 4096
#define PS 4128            // padded hT row stride in elems (breaks 8KB L1 aliasing)
#define FIN 128
#define FOUT 64
#define H 8
#define ALPHA 0.2f

typedef __attribute__((ext_vector_type(2)))  _Float16 f16x2;
typedef __attribute__((ext_vector_type(8)))  _Float16 f16x8;
typedef __attribute__((ext_vector_type(16))) float    f32x16;

__device__ __forceinline__ unsigned short f2h(float x) {
    return __builtin_bit_cast(unsigned short, (_Float16)x);  // RTNE
}

// ---------------------------------------------------------------------------
// k_proj: h = X·W (fp32), hT[h][f][j] fp16 with padded row stride PS;
// f1=h·a1, f2=h·a2 -> E1h[i][h]=(e^f1,e^{a f1}); E2p[h][j]=(e^f2,e^{a f2}).
// ---------------------------------------------------------------------------
__global__ __launch_bounds__(256) void k_proj(const float* __restrict__ X,
                                              const float* __restrict__ W,
                                              const float* __restrict__ a1,
                                              const float* __restrict__ a2,
                                              unsigned short* __restrict__ hT,
                                              float2* __restrict__ E1h,
                                              float2* __restrict__ E2p) {
    __shared__ float xs[64][36];
    __shared__ float Ws[32][68];
    const int h  = blockIdx.y;
    const int j0 = blockIdx.x * 64;
    const int t  = threadIdx.x;
    const int fg = t & 15, rg = t >> 4;
    const int jr = t >> 2, q = t & 3;
    const int kw = t >> 3, cw = t & 7;
    float acc[4][4] = {};
#pragma unroll
    for (int k0 = 0; k0 < FIN; k0 += 32) {
        *(float4*)&xs[jr][q * 8]      = *(const float4*)&X[(j0 + jr) * FIN + k0 + q * 8];
        *(float4*)&xs[jr][q * 8 + 4]  = *(const float4*)&X[(j0 + jr) * FIN + k0 + q * 8 + 4];
        *(float4*)&Ws[kw][cw * 8]     = *(const float4*)&W[(h * FIN + k0 + kw) * FOUT + cw * 8];
        *(float4*)&Ws[kw][cw * 8 + 4] = *(const float4*)&W[(h * FIN + k0 + kw) * FOUT + cw * 8 + 4];
        __syncthreads();
#pragma unroll
        for (int kc = 0; kc < 8; ++kc) {
            float4 xr[4], wr[4];
#pragma unroll
            for (int r = 0; r < 4; ++r) xr[r] = *(const float4*)&xs[4 * rg + r][kc * 4];
#pragma unroll
            for (int kk = 0; kk < 4; ++kk) wr[kk] = *(const float4*)&Ws[kc * 4 + kk][fg * 4];
#pragma unroll
            for (int r = 0; r < 4; ++r) {
                const float* xp = (const float*)&xr[r];
#pragma unroll
                for (int kk = 0; kk < 4; ++kk) {
                    const float xv = xp[kk];
                    acc[r][0] += xv * wr[kk].x;
                    acc[r][1] += xv * wr[kk].y;
                    acc[r][2] += xv * wr[kk].z;
                    acc[r][3] += xv * wr[kk].w;
                }
            }
        }
        __syncthreads();
    }
    const float4 a1v = *(const float4*)&a1[h * FOUT + fg * 4];
    const float4 a2v = *(const float4*)&a2[h * FOUT + fg * 4];
#pragma unroll
    for (int r = 0; r < 4; ++r) {
        float p1 = acc[r][0] * a1v.x + acc[r][1] * a1v.y + acc[r][2] * a1v.z + acc[r][3] * a1v.w;
        float p2 = acc[r][0] * a2v.x + acc[r][1] * a2v.y + acc[r][2] * a2v.z + acc[r][3] * a2v.w;
#pragma unroll
        for (int off = 1; off < 16; off <<= 1) {
            p1 += __shfl_xor(p1, off, 64);
            p2 += __shfl_xor(p2, off, 64);
        }
        if (fg == 0) {
            const int row = j0 + 4 * rg + r;
            E1h[(size_t)row * H + h] = make_float2(__expf(p1), __expf(ALPHA * p1));
            E2p[h * S + row]         = make_float2(__expf(p2), __expf(ALPHA * p2));
        }
    }
#pragma unroll
    for (int c = 0; c < 4; ++c) {
        ushort4 pk;
        pk.x = f2h(acc[0][c]);
        pk.y = f2h(acc[1][c]);
        pk.z = f2h(acc[2][c]);
        pk.w = f2h(acc[3][c]);
        *(ushort4*)&hT[(size_t)(h * FOUT + fg * 4 + c) * PS + j0 + 4 * rg] = pk;
    }
}

// ---------------------------------------------------------------------------
// k_colsum: Dpart[z,h,j] = sum_{i in chunk z} adj(i,j)*max(E1x*E2x, E1y*E2y);
// packs adj into TRANSPOSED bitmask bmT[jword][i].
// grid (S/64 j-tiles, S/256 i-chunks), 256 thr.
// ---------------------------------------------------------------------------
__global__ __launch_bounds__(256) void k_colsum(const int* __restrict__ adj,
                                                const float2* __restrict__ E1h,
                                                const float2* __restrict__ E2p,
                                                float* __restrict__ Dpart,
                                                unsigned int* __restrict__ bmT) {
    __shared__ float red[4][H][64];
    const int j0    = blockIdx.x * 64;
    const int ibase = blockIdx.y * 256;
    const int t  = threadIdx.x;
    const int jl = t & 63;
    const int wv = __builtin_amdgcn_readfirstlane(t >> 6);
    float2 e2v[H];
    float Dl[H];
#pragma unroll
    for (int hh = 0; hh < H; ++hh) { e2v[hh] = E2p[hh * S + j0 + jl]; Dl[hh] = 0.f; }
    const int rowbase = ibase + wv * 64;
    for (int s = 0; s < 64; ++s) {
        const int row = rowbase + s;
        const float2* __restrict__ e1r = E1h + (size_t)row * H;  // wave-uniform
        const int av = adj[(size_t)row * S + j0 + jl];
        const unsigned long long blt = __ballot(av != 0);
        if (jl == 0) {
            bmT[(j0 >> 5) * S + row]       = (unsigned int)blt;
            bmT[((j0 >> 5) + 1) * S + row] = (unsigned int)(blt >> 32);
        }
        const float bf = av != 0 ? 1.f : 0.f;
#pragma unroll
        for (int hh = 0; hh < H; ++hh) {
            const float2 e1 = e1r[hh];
            Dl[hh] = fmaf(bf, fmaxf(e1.x * e2v[hh].x, e1.y * e2v[hh].y), Dl[hh]);
        }
    }
#pragma unroll
    for (int hh = 0; hh < H; ++hh) red[wv][hh][jl] = Dl[hh];
    __syncthreads();
    if (wv == 0) {
#pragma unroll
        for (int hh = 0; hh < H; ++hh) {
            const float sum = red[0][hh][jl] + red[1][hh][jl] +
                              red[2][hh][jl] + red[3][hh][jl];
            Dpart[(blockIdx.y * H + hh) * S + j0 + jl] = sum;
        }
    }
}

// ---------------------------------------------------------------------------
// k_finish: wE2h[h][pair] = { h2(qx_j,qx_j1), h2(qy_j,qy_j1) },
// q = E2pair / colsum  (w folded in, packed fp16 SoA pairs for k_attn)
// ---------------------------------------------------------------------------
__global__ __launch_bounds__(256) void k_finish(const float* __restrict__ Dpart,
                                                const float2* __restrict__ E2p,
                                                uint2* __restrict__ wE2h) {
    const int idx = blockIdx.x * 256 + threadIdx.x;   // pair index over H*S/2
    const int hh = idx >> 11, pp = idx & 2047;
    const int j = 2 * pp;
    float sx = 0.f, sy = 0.f;
#pragma unroll
    for (int z = 0; z < 16; ++z) {
        const float2 d = *(const float2*)&Dpart[(z * H + hh) * S + j];
        sx += d.x; sy += d.y;
    }
    const float4 e2 = *(const float4*)&E2p[hh * S + j];  // (x0,y0,x1,y1)
    const float wa = 1.0f / sx, wb = 1.0f / sy;
    f16x2 qx, qy;
    qx[0] = (_Float16)(e2.x * wa); qx[1] = (_Float16)(e2.z * wb);
    qy[0] = (_Float16)(e2.y * wa); qy[1] = (_Float16)(e2.w * wb);
    wE2h[idx] = make_uint2(__builtin_bit_cast(unsigned int, qx),
                           __builtin_bit_cast(unsigned int, qy));
}

// ---------------------------------------------------------------------------
// k_attn: partial[z][i, h*64+f] = sum_{j in half z} P[i,j]*hT[h][f][j],
// mfma 32x32x16 f16.  grid (S/128, H, 2 z-halves) = 512 blocks; 512 thr =
// 2 K-quarters x 4 M-waves -> M=128/block, each staged B-tile shared by 4
// M-waves. Staging coalesced (4 thr/row x 2x16B); LDS XOR-swizzled; ONE
// barrier per 64-j tile with next-tile register prefetch. Bitmask words
// loaded as TWO STRIDED SCALARS (bmT[w][i], bmT[w+1][i]) — R9's uint2 load
// fetched bmT[w][i+1] (row i+1's adjacency!) and broke correctness.
// ---------------------------------------------------------------------------
__global__ __launch_bounds__(512, 4) void k_attn(const unsigned int* __restrict__ bmT,
                                                 const float2* __restrict__ E1h,
                                                 const uint2* __restrict__ wE2h,
                                                 const unsigned short* __restrict__ hT,
                                                 float* __restrict__ outp) {
    __shared__ __align__(16) char smem[40960];   // Bs 32K | wE2s 8K ; reuse for reduce
    const int h  = blockIdx.y;
    const int i0 = blockIdx.x * 128;
    const int z  = blockIdx.z;
    const int t  = threadIdx.x;

    // ---- prologue: this z-half's 1024 wE2 pairs (8 KB) into LDS ----
    uint2* wE2s = (uint2*)(smem + 32768);
    ((uint4*)wE2s)[t] = ((const uint4*)(wE2h + h * (S / 2) + z * 1024))[t];

    const int lane = t & 63, wv = t >> 6;
    const int q  = wv >> 2;            // K-quarter (1024 j each)
    const int mw = wv & 3;             // M-wave (32 rows each)
    const int am = lane & 31, kh = lane >> 5;
    const int i  = i0 + mw * 32 + am;
    const int jbase = z * 2048 + q * 1024;

    const float2 e1 = E1h[(size_t)i * H + h];
    f16x2 ea2, eb2;
    ea2[0] = ea2[1] = (_Float16)e1.x;
    eb2[0] = eb2[1] = (_Float16)e1.y;

    f32x16 acc0 = {0,0,0,0,0,0,0,0,0,0,0,0,0,0,0,0};
    f32x16 acc1 = {0,0,0,0,0,0,0,0,0,0,0,0,0,0,0,0};

    // staging: tq in [0,256) within q-group; 4 threads/row, 2x16B each
    const int tq = t & 255;
    const int sf = tq >> 2;            // f row 0..63
    const int c0 = tq & 3;             // chunks c0 and c0+4 (64B halves of row)
    unsigned short* Bq = (unsigned short*)smem + q * 8192;   // 2 bufs x 4096
    const unsigned short* hstage = hT + (size_t)(h * FOUT + sf) * PS + jbase;

    const unsigned int* bmcol = bmT + (jbase >> 5) * S + i;
    const uint2* e2s = wE2s + q * 512 + kh * 4;
    const unsigned int sh = kh * 8;

    // tile-0 prefetch
    uint4 va = *(const uint4*)(hstage + c0 * 8);
    uint4 vb = *(const uint4*)(hstage + 32 + c0 * 8);
    unsigned int bw0 = bmcol[0];
    unsigned int bw1 = bmcol[S];
    __syncthreads();   // wE2s ready

    for (int jt = 0; jt < 16; ++jt) {
        unsigned short* Bc = Bq + (jt & 1) * 4096;
        // write prefetched tile to LDS (XOR swizzle), then ONE barrier
        *(uint4*)&Bc[sf * 64 + ((c0 ^ (sf & 7)) * 8)]       = va;
        *(uint4*)&Bc[sf * 64 + (((c0 + 4) ^ (sf & 7)) * 8)] = vb;
        const unsigned int m0 = bw0, m1 = bw1;
        __syncthreads();
        // issue next-tile loads; they land during this tile's compute
        if (jt < 15) {
            va  = *(const uint4*)(hstage + (jt + 1) * 64 + c0 * 8);
            vb  = *(const uint4*)(hstage + (jt + 1) * 64 + 32 + c0 * 8);
            bw0 = bmcol[(2 * jt + 2) * S];
            bw1 = bmcol[(2 * jt + 3) * S];
        }
        unsigned int bys[4];
        bys[0] = (m0 >> sh) & 0xffu;
        bys[1] = (m0 >> (sh + 16)) & 0xffu;
        bys[2] = (m1 >> sh) & 0xffu;
        bys[3] = (m1 >> (sh + 16)) & 0xffu;
#pragma unroll
        for (int s = 0; s < 4; ++s) {
            const uint4 eA = *(const uint4*)(e2s + jt * 32 + s * 8);
            const uint4 eB = *(const uint4*)(e2s + jt * 32 + s * 8 + 2);
            const unsigned int by = bys[s];
            uint4 aw;
#define GAT_PAIR(pp, qxu, qyu, dst)                                               \
            {                                                                     \
                const f16x2 pa = ea2 * __builtin_bit_cast(f16x2, qxu);            \
                const f16x2 pb = eb2 * __builtin_bit_cast(f16x2, qyu);            \
                const f16x2 pm = __builtin_elementwise_max(pa, pb);               \
                const unsigned int b2 = (by >> (2 * pp)) & 3u;                    \
                const unsigned int vv = (b2 | (b2 << 15)) & 0x00010001u;          \
                const unsigned int mm = (vv << 14) - (vv << 10); /* x 0x3C00 */   \
                dst = __builtin_bit_cast(unsigned int,                            \
                      pm * __builtin_bit_cast(f16x2, mm));                        \
            }
            GAT_PAIR(0, eA.x, eA.y, aw.x)
            GAT_PAIR(1, eA.z, eA.w, aw.y)
            GAT_PAIR(2, eB.x, eB.y, aw.z)
            GAT_PAIR(3, eB.z, eB.w, aw.w)
#undef GAT_PAIR
            const int chunk = s * 2 + kh;
            const f16x8 a  = __builtin_bit_cast(f16x8, aw);
            const f16x8 b0 = *(const f16x8*)&Bc[am * 64 + ((chunk ^ (am & 7)) * 8)];
            const f16x8 b1 = *(const f16x8*)&Bc[(am + 32) * 64 + ((chunk ^ ((am + 32) & 7)) * 8)];
            acc0 = __builtin_amdgcn_mfma_f32_32x32x16_f16(a, b0, acc0, 0, 0, 0);
            acc1 = __builtin_amdgcn_mfma_f32_32x32x16_f16(a, b1, acc1, 0, 0, 0);
        }
    }
    __syncthreads();   // Bs/wE2s dead; reuse smem for cross-q reduction

    // ---- 2-way cross-quarter reduction (stride 36 floats) ----
    float* r1 = (float*)smem;
    const int ro = (mw * 64 + lane) * 36;
    if (q == 1) {
#pragma unroll
        for (int r = 0; r < 16; ++r) { r1[ro + r] = acc0[r]; r1[ro + 16 + r] = acc1[r]; }
    }
    __syncthreads();
    if (q == 0) {
#pragma unroll
        for (int r = 0; r < 16; ++r) { acc0[r] += r1[ro + r]; acc1[r] += r1[ro + 16 + r]; }
        float* dst = outp + (size_t)z * (S * H * FOUT);
        // C layout (32x32): col = lane&31, row = (r&3) + 8*(r>>2) + 4*(lane>>5)
#pragma unroll
        for (int r = 0; r < 16; ++r) {
            const int il  = (r & 3) + 8 * (r >> 2) + 4 * kh;
            const int row = i0 + mw * 32 + il;
            dst[row * (H * FOUT) + h * FOUT + am]      = acc0[r];
            dst[row * (H * FOUT) + h * FOUT + 32 + am] = acc1[r];
        }
    }
}

// ---------------------------------------------------------------------------
// k_elu: out = elu(partial0 + partial1)
// ---------------------------------------------------------------------------
__global__ __launch_bounds__(256) void k_elu(const float* __restrict__ outp,
                                             float* __restrict__ out) {
    const int idx = (blockIdx.x * 256 + threadIdx.x) * 4;
    const float4 p0 = *(const float4*)&outp[idx];
    const float4 p1 = *(const float4*)&outp[S * H * FOUT + idx];
    float4 v;
    v.x = p0.x + p1.x; v.y = p0.y + p1.y; v.z = p0.z + p1.z; v.w = p0.w + p1.w;
    v.x = v.x > 0.f ? v.x : __expf(v.x) - 1.f;
    v.y = v.y > 0.f ? v.y : __expf(v.y) - 1.f;
    v.z = v.z > 0.f ? v.z : __expf(v.z) - 1.f;
    v.w = v.w > 0.f ? v.w : __expf(v.w) - 1.f;
    *(float4*)&out[idx] = v;
}

extern "C" void kernel_launch(void* const* d_in, const int* in_sizes, int n_in,
                              void* d_out, int out_size, void* d_ws, size_t ws_size,
                              hipStream_t stream) {
    const float* X   = (const float*)d_in[0];  // [1,4096,128]
    const int*   adj = (const int*)d_in[1];    // [1,4096,4096]
    const float* W   = (const float*)d_in[2];  // [8,128,64]
    const float* a1  = (const float*)d_in[3];  // [8,64,1]
    const float* a2  = (const float*)d_in[4];  // [8,64,1]
    float* out = (float*)d_out;                // [4096, 512]

    char* ws = (char*)d_ws;
    unsigned short* hT   = (unsigned short*)ws;               // ≈4.03 MB fp16, PS stride
    float2*         E1h  = (float2*)(ws + 4325376);           // 256 KB [i][h]
    float2*         E2p  = (float2*)(ws + 4587520);           // 256 KB [h][j]
    float*          Dpart= (float*)(ws + 4849664);            // 2 MB [z16][h][j]
    unsigned int*   bmT  = (unsigned int*)(ws + 6946816);     // 2 MB [jword][i]
    uint2*          wE2h = (uint2*)(ws + 9043968);            // 128 KB [h][pair]
    float*          outp = (float*)(ws + 9175040);            // 16 MB [z2][i][hf]
    // total ~25.7 MB

    k_proj  <<<dim3(S / 64, H),       256, 0, stream>>>(X, W, a1, a2, hT, E1h, E2p);
    k_colsum<<<dim3(S / 64, S / 256), 256, 0, stream>>>(adj, E1h, E2p, Dpart, bmT);
    k_finish<<<dim3(H * S / 512),     256, 0, stream>>>(Dpart, E2p, wE2h);
    k_attn  <<<dim3(S / 128, H, 2),   512, 0, stream>>>(bmT, E1h, wE2h, hT, outp);
    k_elu   <<<dim3(S * H * FOUT / 1024), 256, 0, stream>>>(outp, out);
}

// Round 11
// 174.108 us; speedup vs baseline: 2.5618x; 1.0996x over previous
//
#include <hip/hip_runtime.h>

#define S 4096
#define PS 4128            // padded hT row stride in elems (breaks 8KB L1 aliasing)
#define FIN 128
#define FOUT 64
#define H 8
#define ALPHA 0.2f

typedef __attribute__((ext_vector_type(2)))  _Float16 f16x2;
typedef __attribute__((ext_vector_type(8)))  _Float16 f16x8;
typedef __attribute__((ext_vector_type(16))) float    f32x16;

__device__ __forceinline__ unsigned short f2h(float x) {
    return __builtin_bit_cast(unsigned short, (_Float16)x);  // RTNE
}

// ---------------------------------------------------------------------------
// k_proj: h = X·W (fp32), hT[h][f][j] fp16 with padded row stride PS;
// f1=h·a1, f2=h·a2 -> E1h[i][h]=(e^f1,e^{a f1}); E2p[h][j]=(e^f2,e^{a f2}).
// ---------------------------------------------------------------------------
__global__ __launch_bounds__(256) void k_proj(const float* __restrict__ X,
                                              const float* __restrict__ W,
                                              const float* __restrict__ a1,
                                              const float* __restrict__ a2,
                                              unsigned short* __restrict__ hT,
                                              float2* __restrict__ E1h,
                                              float2* __restrict__ E2p) {
    __shared__ float xs[64][36];
    __shared__ float Ws[32][68];
    const int h  = blockIdx.y;
    const int j0 = blockIdx.x * 64;
    const int t  = threadIdx.x;
    const int fg = t & 15, rg = t >> 4;
    const int jr = t >> 2, q = t & 3;
    const int kw = t >> 3, cw = t & 7;
    float acc[4][4] = {};
#pragma unroll
    for (int k0 = 0; k0 < FIN; k0 += 32) {
        *(float4*)&xs[jr][q * 8]      = *(const float4*)&X[(j0 + jr) * FIN + k0 + q * 8];
        *(float4*)&xs[jr][q * 8 + 4]  = *(const float4*)&X[(j0 + jr) * FIN + k0 + q * 8 + 4];
        *(float4*)&Ws[kw][cw * 8]     = *(const float4*)&W[(h * FIN + k0 + kw) * FOUT + cw * 8];
        *(float4*)&Ws[kw][cw * 8 + 4] = *(const float4*)&W[(h * FIN + k0 + kw) * FOUT + cw * 8 + 4];
        __syncthreads();
#pragma unroll
        for (int kc = 0; kc < 8; ++kc) {
            float4 xr[4], wr[4];
#pragma unroll
            for (int r = 0; r < 4; ++r) xr[r] = *(const float4*)&xs[4 * rg + r][kc * 4];
#pragma unroll
            for (int kk = 0; kk < 4; ++kk) wr[kk] = *(const float4*)&Ws[kc * 4 + kk][fg * 4];
#pragma unroll
            for (int r = 0; r < 4; ++r) {
                const float* xp = (const float*)&xr[r];
#pragma unroll
                for (int kk = 0; kk < 4; ++kk) {
                    const float xv = xp[kk];
                    acc[r][0] += xv * wr[kk].x;
                    acc[r][1] += xv * wr[kk].y;
                    acc[r][2] += xv * wr[kk].z;
                    acc[r][3] += xv * wr[kk].w;
                }
            }
        }
        __syncthreads();
    }
    const float4 a1v = *(const float4*)&a1[h * FOUT + fg * 4];
    const float4 a2v = *(const float4*)&a2[h * FOUT + fg * 4];
#pragma unroll
    for (int r = 0; r < 4; ++r) {
        float p1 = acc[r][0] * a1v.x + acc[r][1] * a1v.y + acc[r][2] * a1v.z + acc[r][3] * a1v.w;
        float p2 = acc[r][0] * a2v.x + acc[r][1] * a2v.y + acc[r][2] * a2v.z + acc[r][3] * a2v.w;
#pragma unroll
        for (int off = 1; off < 16; off <<= 1) {
            p1 += __shfl_xor(p1, off, 64);
            p2 += __shfl_xor(p2, off, 64);
        }
        if (fg == 0) {
            const int row = j0 + 4 * rg + r;
            E1h[(size_t)row * H + h] = make_float2(__expf(p1), __expf(ALPHA * p1));
            E2p[h * S + row]         = make_float2(__expf(p2), __expf(ALPHA * p2));
        }
    }
#pragma unroll
    for (int c = 0; c < 4; ++c) {
        ushort4 pk;
        pk.x = f2h(acc[0][c]);
        pk.y = f2h(acc[1][c]);
        pk.z = f2h(acc[2][c]);
        pk.w = f2h(acc[3][c]);
        *(ushort4*)&hT[(size_t)(h * FOUT + fg * 4 + c) * PS + j0 + 4 * rg] = pk;
    }
}

// ---------------------------------------------------------------------------
// k_colsum: Dpart[z,h,j] = sum_{i in chunk z} adj(i,j)*max(E1x*E2x, E1y*E2y);
// packs adj into TRANSPOSED bitmask bmT[jword][i].
// R11: latency fix — 8 independent adj row-loads in flight per wave (manual
// unroll x8) and 2x grid (i-chunk 128 -> 2048 blocks = 8 blocks/CU = 32
// waves/CU). grid (S/64 j-tiles, S/128 i-chunks), 256 thr, 32 rows/wave.
// ---------------------------------------------------------------------------
__global__ __launch_bounds__(256) void k_colsum(const int* __restrict__ adj,
                                                const float2* __restrict__ E1h,
                                                const float2* __restrict__ E2p,
                                                float* __restrict__ Dpart,
                                                unsigned int* __restrict__ bmT) {
    __shared__ float red[4][H][64];
    const int j0    = blockIdx.x * 64;
    const int ibase = blockIdx.y * 128;
    const int t  = threadIdx.x;
    const int jl = t & 63;
    const int wv = __builtin_amdgcn_readfirstlane(t >> 6);
    float2 e2v[H];
    float Dl[H];
#pragma unroll
    for (int hh = 0; hh < H; ++hh) { e2v[hh] = E2p[hh * S + j0 + jl]; Dl[hh] = 0.f; }
    const int rowbase = ibase + wv * 32;
    for (int s = 0; s < 32; s += 8) {
        int av[8];
#pragma unroll
        for (int u = 0; u < 8; ++u)
            av[u] = adj[(size_t)(rowbase + s + u) * S + j0 + jl];
#pragma unroll
        for (int u = 0; u < 8; ++u) {
            const int row = rowbase + s + u;
            const float2* __restrict__ e1r = E1h + (size_t)row * H;  // wave-uniform
            const unsigned long long blt = __ballot(av[u] != 0);
            if (jl == 0) {
                bmT[(j0 >> 5) * S + row]       = (unsigned int)blt;
                bmT[((j0 >> 5) + 1) * S + row] = (unsigned int)(blt >> 32);
            }
            const float bf = av[u] != 0 ? 1.f : 0.f;
#pragma unroll
            for (int hh = 0; hh < H; ++hh) {
                const float2 e1 = e1r[hh];
                Dl[hh] = fmaf(bf, fmaxf(e1.x * e2v[hh].x, e1.y * e2v[hh].y), Dl[hh]);
            }
        }
    }
#pragma unroll
    for (int hh = 0; hh < H; ++hh) red[wv][hh][jl] = Dl[hh];
    __syncthreads();
    if (wv == 0) {
#pragma unroll
        for (int hh = 0; hh < H; ++hh) {
            const float sum = red[0][hh][jl] + red[1][hh][jl] +
                              red[2][hh][jl] + red[3][hh][jl];
            Dpart[(blockIdx.y * H + hh) * S + j0 + jl] = sum;
        }
    }
}

// ---------------------------------------------------------------------------
// k_finish: wE2h[h][pair] = { h2(qx_j,qx_j1), h2(qy_j,qy_j1) },
// q = E2pair / colsum  (w folded in, packed fp16 SoA pairs for k_attn)
// ---------------------------------------------------------------------------
__global__ __launch_bounds__(256) void k_finish(const float* __restrict__ Dpart,
                                                const float2* __restrict__ E2p,
                                                uint2* __restrict__ wE2h) {
    const int idx = blockIdx.x * 256 + threadIdx.x;   // pair index over H*S/2
    const int hh = idx >> 11, pp = idx & 2047;
    const int j = 2 * pp;
    float sx = 0.f, sy = 0.f;
#pragma unroll
    for (int z = 0; z < 32; ++z) {
        const float2 d = *(const float2*)&Dpart[(z * H + hh) * S + j];
        sx += d.x; sy += d.y;
    }
    const float4 e2 = *(const float4*)&E2p[hh * S + j];  // (x0,y0,x1,y1)
    const float wa = 1.0f / sx, wb = 1.0f / sy;
    f16x2 qx, qy;
    qx[0] = (_Float16)(e2.x * wa); qx[1] = (_Float16)(e2.z * wb);
    qy[0] = (_Float16)(e2.y * wa); qy[1] = (_Float16)(e2.w * wb);
    wE2h[idx] = make_uint2(__builtin_bit_cast(unsigned int, qx),
                           __builtin_bit_cast(unsigned int, qy));
}

// ---------------------------------------------------------------------------
// k_attn: partial[z][i, h*64+f] = sum_{j in half z} P[i,j]*hT[h][f][j],
// mfma 32x32x16 f16.  grid (S/128, H, 2 z-halves) = 512 blocks; 512 thr =
// 2 K-quarters x 4 M-waves -> M=128/block, each staged B-tile shared by 4
// M-waves. Staging coalesced (4 thr/row x 2x16B); LDS XOR-swizzled; ONE
// barrier per 64-j tile with next-tile register prefetch. Bitmask words
// loaded as TWO STRIDED SCALARS (bmT[w][i], bmT[w+1][i]).
// ---------------------------------------------------------------------------
__global__ __launch_bounds__(512, 4) void k_attn(const unsigned int* __restrict__ bmT,
                                                 const float2* __restrict__ E1h,
                                                 const uint2* __restrict__ wE2h,
                                                 const unsigned short* __restrict__ hT,
                                                 float* __restrict__ outp) {
    __shared__ __align__(16) char smem[40960];   // Bs 32K | wE2s 8K ; reuse for reduce
    const int h  = blockIdx.y;
    const int i0 = blockIdx.x * 128;
    const int z  = blockIdx.z;
    const int t  = threadIdx.x;

    // ---- prologue: this z-half's 1024 wE2 pairs (8 KB) into LDS ----
    uint2* wE2s = (uint2*)(smem + 32768);
    ((uint4*)wE2s)[t] = ((const uint4*)(wE2h + h * (S / 2) + z * 1024))[t];

    const int lane = t & 63, wv = t >> 6;
    const int q  = wv >> 2;            // K-quarter (1024 j each)
    const int mw = wv & 3;             // M-wave (32 rows each)
    const int am = lane & 31, kh = lane >> 5;
    const int i  = i0 + mw * 32 + am;
    const int jbase = z * 2048 + q * 1024;

    const float2 e1 = E1h[(size_t)i * H + h];
    f16x2 ea2, eb2;
    ea2[0] = ea2[1] = (_Float16)e1.x;
    eb2[0] = eb2[1] = (_Float16)e1.y;

    f32x16 acc0 = {0,0,0,0,0,0,0,0,0,0,0,0,0,0,0,0};
    f32x16 acc1 = {0,0,0,0,0,0,0,0,0,0,0,0,0,0,0,0};

    // staging: tq in [0,256) within q-group; 4 threads/row, 2x16B each
    const int tq = t & 255;
    const int sf = tq >> 2;            // f row 0..63
    const int c0 = tq & 3;             // chunks c0 and c0+4 (64B halves of row)
    unsigned short* Bq = (unsigned short*)smem + q * 8192;   // 2 bufs x 4096
    const unsigned short* hstage = hT + (size_t)(h * FOUT + sf) * PS + jbase;

    const unsigned int* bmcol = bmT + (jbase >> 5) * S + i;
    const uint2* e2s = wE2s + q * 512 + kh * 4;
    const unsigned int sh = kh * 8;

    // tile-0 prefetch
    uint4 va = *(const uint4*)(hstage + c0 * 8);
    uint4 vb = *(const uint4*)(hstage + 32 + c0 * 8);
    unsigned int bw0 = bmcol[0];
    unsigned int bw1 = bmcol[S];
    __syncthreads();   // wE2s ready

    for (int jt = 0; jt < 16; ++jt) {
        unsigned short* Bc = Bq + (jt & 1) * 4096;
        // write prefetched tile to LDS (XOR swizzle), then ONE barrier
        *(uint4*)&Bc[sf * 64 + ((c0 ^ (sf & 7)) * 8)]       = va;
        *(uint4*)&Bc[sf * 64 + (((c0 + 4) ^ (sf & 7)) * 8)] = vb;
        const unsigned int m0 = bw0, m1 = bw1;
        __syncthreads();
        // issue next-tile loads; they land during this tile's compute
        if (jt < 15) {
            va  = *(const uint4*)(hstage + (jt + 1) * 64 + c0 * 8);
            vb  = *(const uint4*)(hstage + (jt + 1) * 64 + 32 + c0 * 8);
            bw0 = bmcol[(2 * jt + 2) * S];
            bw1 = bmcol[(2 * jt + 3) * S];
        }
        unsigned int bys[4];
        bys[0] = (m0 >> sh) & 0xffu;
        bys[1] = (m0 >> (sh + 16)) & 0xffu;
        bys[2] = (m1 >> sh) & 0xffu;
        bys[3] = (m1 >> (sh + 16)) & 0xffu;
#pragma unroll
        for (int s = 0; s < 4; ++s) {
            const uint4 eA = *(const uint4*)(e2s + jt * 32 + s * 8);
            const uint4 eB = *(const uint4*)(e2s + jt * 32 + s * 8 + 2);
            const unsigned int by = bys[s];
            uint4 aw;
#define GAT_PAIR(pp, qxu, qyu, dst)                                               \
            {                                                                     \
                const f16x2 pa = ea2 * __builtin_bit_cast(f16x2, qxu);            \
                const f16x2 pb = eb2 * __builtin_bit_cast(f16x2, qyu);            \
                const f16x2 pm = __builtin_elementwise_max(pa, pb);               \
                const unsigned int b2 = (by >> (2 * pp)) & 3u;                    \
                const unsigned int vv = (b2 | (b2 << 15)) & 0x00010001u;          \
                const unsigned int mm = (vv << 14) - (vv << 10); /* x 0x3C00 */   \
                dst = __builtin_bit_cast(unsigned int,                            \
                      pm * __builtin_bit_cast(f16x2, mm));                        \
            }
            GAT_PAIR(0, eA.x, eA.y, aw.x)
            GAT_PAIR(1, eA.z, eA.w, aw.y)
            GAT_PAIR(2, eB.x, eB.y, aw.z)
            GAT_PAIR(3, eB.z, eB.w, aw.w)
#undef GAT_PAIR
            const int chunk = s * 2 + kh;
            const f16x8 a  = __builtin_bit_cast(f16x8, aw);
            const f16x8 b0 = *(const f16x8*)&Bc[am * 64 + ((chunk ^ (am & 7)) * 8)];
            const f16x8 b1 = *(const f16x8*)&Bc[(am + 32) * 64 + ((chunk ^ ((am + 32) & 7)) * 8)];
            acc0 = __builtin_amdgcn_mfma_f32_32x32x16_f16(a, b0, acc0, 0, 0, 0);
            acc1 = __builtin_amdgcn_mfma_f32_32x32x16_f16(a, b1, acc1, 0, 0, 0);
        }
    }
    __syncthreads();   // Bs/wE2s dead; reuse smem for cross-q reduction

    // ---- 2-way cross-quarter reduction (stride 36 floats) ----
    float* r1 = (float*)smem;
    const int ro = (mw * 64 + lane) * 36;
    if (q == 1) {
#pragma unroll
        for (int r = 0; r < 16; ++r) { r1[ro + r] = acc0[r]; r1[ro + 16 + r] = acc1[r]; }
    }
    __syncthreads();
    if (q == 0) {
#pragma unroll
        for (int r = 0; r < 16; ++r) { acc0[r] += r1[ro + r]; acc1[r] += r1[ro + 16 + r]; }
        float* dst = outp + (size_t)z * (S * H * FOUT);
        // C layout (32x32): col = lane&31, row = (r&3) + 8*(r>>2) + 4*(lane>>5)
#pragma unroll
        for (int r = 0; r < 16; ++r) {
            const int il  = (r & 3) + 8 * (r >> 2) + 4 * kh;
            const int row = i0 + mw * 32 + il;
            dst[row * (H * FOUT) + h * FOUT + am]      = acc0[r];
            dst[row * (H * FOUT) + h * FOUT + 32 + am] = acc1[r];
        }
    }
}

// ---------------------------------------------------------------------------
// k_elu: out = elu(partial0 + partial1)
// ---------------------------------------------------------------------------
__global__ __launch_bounds__(256) void k_elu(const float* __restrict__ outp,
                                             float* __restrict__ out) {
    const int idx = (blockIdx.x * 256 + threadIdx.x) * 4;
    const float4 p0 = *(const float4*)&outp[idx];
    const float4 p1 = *(const float4*)&outp[S * H * FOUT + idx];
    float4 v;
    v.x = p0.x + p1.x; v.y = p0.y + p1.y; v.z = p0.z + p1.z; v.w = p0.w + p1.w;
    v.x = v.x > 0.f ? v.x : __expf(v.x) - 1.f;
    v.y = v.y > 0.f ? v.y : __expf(v.y) - 1.f;
    v.z = v.z > 0.f ? v.z : __expf(v.z) - 1.f;
    v.w = v.w > 0.f ? v.w : __expf(v.w) - 1.f;
    *(float4*)&out[idx] = v;
}

extern "C" void kernel_launch(void* const* d_in, const int* in_sizes, int n_in,
                              void* d_out, int out_size, void* d_ws, size_t ws_size,
                              hipStream_t stream) {
    const float* X   = (const float*)d_in[0];  // [1,4096,128]
    const int*   adj = (const int*)d_in[1];    // [1,4096,4096]
    const float* W   = (const float*)d_in[2];  // [8,128,64]
    const float* a1  = (const float*)d_in[3];  // [8,64,1]
    const float* a2  = (const float*)d_in[4];  // [8,64,1]
    float* out = (float*)d_out;                // [4096, 512]

    char* ws = (char*)d_ws;
    unsigned short* hT   = (unsigned short*)ws;               // ≈4.03 MB fp16, PS stride
    float2*         E1h  = (float2*)(ws + 4325376);           // 256 KB [i][h]
    float2*         E2p  = (float2*)(ws + 4587520);           // 256 KB [h][j]
    float*          Dpart= (float*)(ws + 4849664);            // 4 MB [z32][h][j]
    unsigned int*   bmT  = (unsigned int*)(ws + 9043968);     // 2 MB [jword][i]
    uint2*          wE2h = (uint2*)(ws + 11141120);           // 128 KB [h][pair]
    float*          outp = (float*)(ws + 11272192);           // 16 MB [z2][i][hf]
    // total ~27.7 MB

    k_proj  <<<dim3(S / 64, H),       256, 0, stream>>>(X, W, a1, a2, hT, E1h, E2p);
    k_colsum<<<dim3(S / 64, S / 128), 256, 0, stream>>>(adj, E1h, E2p, Dpart, bmT);
    k_finish<<<dim3(H * S / 512),     256, 0, stream>>>(Dpart, E2p, wE2h);
    k_attn  <<<dim3(S / 128, H, 2),   512, 0, stream>>>(bmT, E1h, wE2h, hT, outp);
    k_elu   <<<dim3(S * H * FOUT / 1024), 256, 0, stream>>>(outp, out);
}